// Round 16
// baseline (4421.584 us; speedup 1.0000x reference)
//
#include <hip/hip_runtime.h>

// CTRNN fused, v12b = K-split wave specialization for 4 waves/SIMD (compile+idx fix).
// wg = 512 thr = 8 waves (ks,cg): wave holds HALF of Wh (64 AGPR, kt in [4ks,4ks+4)),
// computes partial acc over its K-half (16 MFMA), exchanges non-owned s-subtile
// partials via LDS f32 (pbuf), finishes tanh + h-write for 2 owned s-subtiles.
// Grid 512 (32 bg x 16 ck) = 2 wgs/CU = 16 waves/CU. WARM=24, CHUNK=64.

#define T_ 1024
#define I_ 64
#define H_ 256
#define C_ 5
#define WARM_ 24
#define CHUNK_ 64

typedef float f32x4 __attribute__((ext_vector_type(4)));
typedef __bf16 bf16x8 __attribute__((ext_vector_type(8)));
typedef __bf16 bf16x4 __attribute__((ext_vector_type(4)));
typedef unsigned short ushort_t;
typedef ushort_t ushort8 __attribute__((ext_vector_type(8)));

__device__ __forceinline__ ushort_t f2bf(float x) {  // setup only
  unsigned u = __builtin_bit_cast(unsigned, x);
  return (ushort_t)((u + 0x7FFFu + ((u >> 16) & 1u)) >> 16);
}
__device__ __forceinline__ void bar_lds() {
  __builtin_amdgcn_sched_barrier(0);
  asm volatile("s_waitcnt lgkmcnt(0)" ::: "memory");
  __builtin_amdgcn_s_barrier();
  __builtin_amdgcn_sched_barrier(0);
}
#define MFMA(a, b, c) __builtin_amdgcn_mfma_f32_16x16x32_bf16((a), (b), (c), 0, 0, 0)

__launch_bounds__(512, 4)
__global__ void ctrnn_fused(const float* __restrict__ x, const float* __restrict__ W,
                            const float* __restrict__ bh, const float* __restrict__ Wfc,
                            const float* __restrict__ bfc, float* __restrict__ out) {
  __shared__ __align__(16) char hbuf[2][16 * 256 * 2];     // 16KB, swizzled
  __shared__ __align__(16) char xls[16 * 64 * 2];          // 2KB
  __shared__ __align__(16) char wxl[2 * 4 * 4 * 64 * 16];  // 32KB
  __shared__ __align__(16) char wfl[8 * 64 * 16];          // 8KB
  __shared__ __align__(16) char pbuf[4 * 4 * 64 * 16];     // 16KB f32 partials
  __shared__ __align__(16) float bhl[H_];                  // 1KB
  __shared__ float red[8][16][C_];                         // 2.5KB

  const int tid = threadIdx.x;
  const int w   = tid >> 6;      // wave 0..7
  const int ks  = w >> 2;        // K-half
  const int cg  = w & 3;         // col group
  const int l   = tid & 63;
  const int lr  = l & 15;
  const int lq  = l >> 4;
  const int so  = ks * 2;        // owned s base {0,1} or {2,3}
  const int sa  = 2 - ks * 2;    // not-owned s base
  const int bg  = blockIdx.x & 31;
  const int ck  = blockIdx.x >> 5;
  const int b0  = bg << 4;
  const int tout = ck << 6;
  const int t0   = (ck == 0) ? 0 : (tout - WARM_);
  const int tend = tout + CHUNK_;

  const f32x4 ZERO4 = {0.f, 0.f, 0.f, 0.f};

  // ---- wh half-fragments (64 AGPR): kt_global = ks*4 + kt ----
  bf16x8 wh[4][4];
#pragma unroll
  for (int kt = 0; kt < 4; ++kt)
#pragma unroll
    for (int s = 0; s < 4; ++s) {
      ushort8 tmp;
#pragma unroll
      for (int j = 0; j < 8; ++j) {
        int k = (ks * 4 + kt) * 32 + lq * 8 + j;
        int col = cg * 64 + s * 16 + lr;
        tmp[j] = f2bf(W[(size_t)(I_ + k) * H_ + col]);
      }
      wh[kt][s] = __builtin_bit_cast(bf16x8, tmp);
    }
  // wx fragments -> LDS (each wave stages its owned s)
#pragma unroll
  for (int kt = 0; kt < 2; ++kt)
#pragma unroll
    for (int i = 0; i < 2; ++i) {
      int s = so + i;
      ushort8 tmp;
#pragma unroll
      for (int j = 0; j < 8; ++j) {
        int k = kt * 32 + lq * 8 + j;
        int col = cg * 64 + s * 16 + lr;
        tmp[j] = f2bf(W[(size_t)k * H_ + col]);
      }
      *(bf16x8*)(wxl + (((kt * 4 + s) * 4 + cg) * 64 + l) * 16) =
          __builtin_bit_cast(bf16x8, tmp);
    }
  // wf fragments -> LDS: wave w covers K chunk [32w, 32w+32)
  {
    ushort8 tmp;
#pragma unroll
    for (int j = 0; j < 8; ++j) {
      int k = w * 32 + lq * 8 + j;
      tmp[j] = (lr < C_) ? f2bf(Wfc[(size_t)k * C_ + lr]) : (ushort_t)0;
    }
    *(bf16x8*)(wfl + (w * 64 + l) * 16) = __builtin_bit_cast(bf16x8, tmp);
  }
  if (tid < 64) *(float4*)(bhl + tid * 4) = *(const float4*)(bh + tid * 4);

  ((uint4*)hbuf[0])[tid] = (uint4){0, 0, 0, 0};  // 512 x 16B = 8KB

  // x staging: 512 threads, float2 each: row = tid>>5, chunk = tid&31
  const int xrow = tid >> 5, xc2 = tid & 31;
  const float* xbase = x + (size_t)(b0 + xrow) * T_ * I_ + xc2 * 2;
  float2 xpre = *(const float2*)(xbase + (size_t)t0 * I_);
  {
    int byte = xrow * 128 + xc2 * 4;
    byte ^= (xrow & 7) << 4;
    ushort_t p0 = f2bf(xpre.x), p1 = f2bf(xpre.y);
    *(unsigned*)(xls + byte) = (unsigned)p0 | ((unsigned)p1 << 16);
  }
  __syncthreads();

  // xw(t0) for owned s
  f32x4 xw[2];
  {
    bf16x8 xa[2];
#pragma unroll
    for (int kt = 0; kt < 2; ++kt) {
      int byte = lr * 128 + (kt * 32 + lq * 8) * 2;
      byte ^= (lr & 7) << 4;
      xa[kt] = *(const bf16x8*)(xls + byte);
    }
#pragma unroll
    for (int i = 0; i < 2; ++i) {
      int s = so + i;
      float4 bi = *(const float4*)(bhl + cg * 64 + s * 16 + lq * 4);
      f32x4 a = (f32x4){bi.x, bi.y, bi.z, bi.w};
#pragma unroll
      for (int kt = 0; kt < 2; ++kt) {
        bf16x8 wxr = *(const bf16x8*)(wxl + (((kt * 4 + s) * 4 + cg) * 64 + l) * 16);
        a = MFMA(wxr, xa[kt], a);
      }
      xw[i] = a;
    }
  }
  xpre = *(const float2*)(xbase + (size_t)(t0 + 1) * I_);

  f32x4 h[2];  // owned cols only
#pragma unroll
  for (int i = 0; i < 2; ++i) h[i] = ZERO4;

  const bool ow = tid < 16 * C_;
  int or_ = 0, oc_ = 0;
  float bfc_r = 0.f;
  if (ow) { or_ = tid / C_; oc_ = tid - or_ * C_; bfc_r = bfc[oc_]; }

  const float TWO_LOG2E = 2.8853900817779268f;

#pragma unroll 1
  for (int tt = t0; tt < tend; ++tt) {
#pragma unroll
    for (int u = 0; u < 6; ++u) {
      const char* hb = hbuf[u & 1];
      // logits(tt-1) at u=0: each wave does K chunk [32w,32w+32), 1 MFMA
      if (u == 0 && tt > tout) {
        int byte = lr * 512 + (w * 32 + lq * 8) * 2;
        byte ^= (lr & 7) << 4;
        bf16x8 hA = *(const bf16x8*)(hb + byte);
        bf16x8 wfr = *(const bf16x8*)(wfl + (w * 64 + l) * 16);
        f32x4 part = MFMA(hA, wfr, ZERO4);
        if (lr < C_) {
#pragma unroll
          for (int jj = 0; jj < 4; ++jj) red[w][lq * 4 + jj][lr] = part[jj];
        }
      }
      // partial acc over K-half
      f32x4 acc[4];
#pragma unroll
      for (int s = 0; s < 4; ++s) acc[s] = ZERO4;
      {
        bf16x8 ha[2];
#pragma unroll
        for (int kt = 0; kt < 2; ++kt) {
          int byte = lr * 512 + ((ks * 4 + kt) * 32 + lq * 8) * 2;
          byte ^= (lr & 7) << 4;
          ha[kt] = *(const bf16x8*)(hb + byte);
        }
#pragma unroll
        for (int kt = 0; kt < 2; ++kt)
#pragma unroll
          for (int s = 0; s < 4; ++s) acc[s] = MFMA(wh[kt][s], ha[kt], acc[s]);
      }
      {
        bf16x8 ha[2];
#pragma unroll
        for (int kt = 2; kt < 4; ++kt) {
          int byte = lr * 512 + ((ks * 4 + kt) * 32 + lq * 8) * 2;
          byte ^= (lr & 7) << 4;
          ha[kt - 2] = *(const bf16x8*)(hb + byte);
        }
#pragma unroll
        for (int kt = 2; kt < 4; ++kt)
#pragma unroll
          for (int s = 0; s < 4; ++s) acc[s] = MFMA(wh[kt][s], ha[kt - 2], acc[s]);
      }
      // export not-owned partials
      *(f32x4*)(pbuf + ((cg * 4 + sa) * 64 + l) * 16)     = acc[sa];
      *(f32x4*)(pbuf + ((cg * 4 + sa + 1) * 64 + l) * 16) = acc[sa + 1];
      bar_lds();

      // store logits(tt-1) at u=1 (red written before u=0's barrier)
      if (u == 1 && tt > tout && ow) {
        float sum = red[0][or_][oc_] + red[1][or_][oc_] + red[2][or_][oc_] +
                    red[3][or_][oc_] + red[4][or_][oc_] + red[5][or_][oc_] +
                    red[6][or_][oc_] + red[7][or_][oc_] + bfc_r;
        out[((size_t)(b0 + or_) * C_ + oc_) * T_ + (tt - 1)] = sum;
      }

      // finish owned s: add partner partial + xw, tanh, h-write
      char* hw = hbuf[(u + 1) & 1];
#pragma unroll
      for (int i = 0; i < 2; ++i) {
        int s = so + i;
        f32x4 p = *(const f32x4*)(pbuf + ((cg * 4 + s) * 64 + l) * 16);
        f32x4 hv;
#pragma unroll
        for (int jj = 0; jj < 4; ++jj) {
          float v = acc[s][jj] + p[jj] + xw[i][jj];
          float e = __builtin_amdgcn_exp2f(v * TWO_LOG2E);
          float r = __builtin_amdgcn_rcpf(e + 1.0f);
          float hn = __builtin_fmaf(-0.2f, r, __builtin_fmaf(0.9f, h[i][jj], 0.1f));
          h[i][jj] = hn;
          hv[jj] = hn;
        }
        int byte = lr * 512 + (cg * 128 + s * 32 + lq * 8);
        byte ^= (lr & 7) << 4;
        bf16x4 pk = {(__bf16)hv[0], (__bf16)hv[1], (__bf16)hv[2], (__bf16)hv[3]};
        *(bf16x4*)(hw + byte) = pk;
      }
      if (u == 5 && tt + 1 < tend) {  // stage x(tt+1)
        int byte = xrow * 128 + xc2 * 4;
        byte ^= (xrow & 7) << 4;
        ushort_t p0 = f2bf(xpre.x), p1 = f2bf(xpre.y);
        *(unsigned*)(xls + byte) = (unsigned)p0 | ((unsigned)p1 << 16);
      }
      bar_lds();
    }

    // xw(tt+1) for owned s — no barrier needed
    if (tt + 1 < tend) {
      bf16x8 xa[2];
#pragma unroll
      for (int kt = 0; kt < 2; ++kt) {
        int byte = lr * 128 + (kt * 32 + lq * 8) * 2;
        byte ^= (lr & 7) << 4;
        xa[kt] = *(const bf16x8*)(xls + byte);
      }
#pragma unroll
      for (int i = 0; i < 2; ++i) {
        int s = so + i;
        float4 bi = *(const float4*)(bhl + cg * 64 + s * 16 + lq * 4);
        f32x4 a = (f32x4){bi.x, bi.y, bi.z, bi.w};
#pragma unroll
        for (int kt = 0; kt < 2; ++kt) {
          bf16x8 wxr = *(const bf16x8*)(wxl + (((kt * 4 + s) * 4 + cg) * 64 + l) * 16);
          a = MFMA(wxr, xa[kt], a);
        }
        xw[i] = a;
      }
      if (tt + 2 < T_) xpre = *(const float2*)(xbase + (size_t)(tt + 2) * I_);
    }
  }

  // epilogue: logits(tend-1)
  {
    const char* hb = hbuf[0];
    int byte = lr * 512 + (w * 32 + lq * 8) * 2;
    byte ^= (lr & 7) << 4;
    bf16x8 hA = *(const bf16x8*)(hb + byte);
    bf16x8 wfr = *(const bf16x8*)(wfl + (w * 64 + l) * 16);
    f32x4 part = MFMA(hA, wfr, ZERO4);
    if (lr < C_) {
#pragma unroll
      for (int jj = 0; jj < 4; ++jj) red[w][lq * 4 + jj][lr] = part[jj];
    }
  }
  bar_lds();
  if (ow) {
    float sum = red[0][or_][oc_] + red[1][or_][oc_] + red[2][or_][oc_] +
                red[3][or_][oc_] + red[4][or_][oc_] + red[5][or_][oc_] +
                red[6][or_][oc_] + red[7][or_][oc_] + bfc_r;
    out[((size_t)(b0 + or_) * C_ + oc_) * T_ + (tend - 1)] = sum;
  }
}

extern "C" void kernel_launch(void* const* d_in, const int* in_sizes, int n_in,
                              void* d_out, int out_size, void* d_ws, size_t ws_size,
                              hipStream_t stream) {
  const float* x   = (const float*)d_in[0];
  const float* W   = (const float*)d_in[1];
  const float* bh  = (const float*)d_in[2];
  const float* Wfc = (const float*)d_in[3];
  const float* bfc = (const float*)d_in[4];
  float* out = (float*)d_out;
  (void)in_sizes; (void)n_in; (void)out_size; (void)d_ws; (void)ws_size;
  ctrnn_fused<<<dim3(512), dim3(512), 0, stream>>>(x, W, bh, Wfc, bfc, out);
}

// Round 17
// 709.333 us; speedup vs baseline: 6.2334x; 6.2334x over previous
//
#include <hip/hip_runtime.h>

// CTRNN fused, v13 = dual-chunk interleave. One wg (256 thr, 4 waves, 1/CU)
// runs TWO independent time-chunks in one instruction stream -> static ILP
// (chunk1 MFMA under chunk0 tanh etc). Weights shared: wh 128 AGPR + dual
// working set fits the 512-reg budget at 1 wave/SIMD -> zero spill.
// Grid 256 (32 bg x 8 chunk-pairs). WARM=24, CHUNK=64. Branchless warm-up
// for chunk0 of pair 0: xw forced 0 => h stays exactly 0.

#define T_ 1024
#define I_ 64
#define H_ 256
#define C_ 5
#define WARM_ 24
#define CHUNK_ 64

typedef float f32x4 __attribute__((ext_vector_type(4)));
typedef __bf16 bf16x8 __attribute__((ext_vector_type(8)));
typedef __bf16 bf16x4 __attribute__((ext_vector_type(4)));
typedef unsigned short ushort_t;
typedef ushort_t ushort8 __attribute__((ext_vector_type(8)));

__device__ __forceinline__ ushort_t f2bf(float x) {  // setup only
  unsigned u = __builtin_bit_cast(unsigned, x);
  return (ushort_t)((u + 0x7FFFu + ((u >> 16) & 1u)) >> 16);
}
__device__ __forceinline__ void bar_lds() {
  __builtin_amdgcn_sched_barrier(0);
  asm volatile("s_waitcnt lgkmcnt(0)" ::: "memory");
  __builtin_amdgcn_s_barrier();
  __builtin_amdgcn_sched_barrier(0);
}
#define MFMA(a, b, c) __builtin_amdgcn_mfma_f32_16x16x32_bf16((a), (b), (c), 0, 0, 0)

__launch_bounds__(256, 1)
__global__ void ctrnn_fused(const float* __restrict__ x, const float* __restrict__ W,
                            const float* __restrict__ bh, const float* __restrict__ Wfc,
                            const float* __restrict__ bfc, float* __restrict__ out) {
  __shared__ __align__(16) char hbuf0[2][16 * 256 * 2];  // 16KB, swizzled
  __shared__ __align__(16) char hbuf1[2][16 * 256 * 2];  // 16KB
  __shared__ __align__(16) char xls0[16 * 64 * 2];       // 2KB
  __shared__ __align__(16) char xls1[16 * 64 * 2];       // 2KB
  __shared__ __align__(16) char wxl[2 * 4 * 4 * 64 * 16];  // 32KB
  __shared__ __align__(16) char wfl[2 * 4 * 64 * 16];      // 8KB
  __shared__ __align__(16) float bhl[H_];                  // 1KB
  __shared__ float red0[4][16][C_];
  __shared__ float red1[4][16][C_];

  const int tid = threadIdx.x;
  const int cg  = tid >> 6;
  const int l   = tid & 63;
  const int lr  = l & 15;
  const int lq  = l >> 4;
  const int bg  = blockIdx.x & 31;   // batch group
  const int ckp = blockIdx.x >> 5;   // chunk pair 0..7
  const int b0  = bg << 4;
  const int tout0 = (ckp * 2) << 6, tend0 = tout0 + CHUNK_, ts0 = tout0 - WARM_;
  const int tout1 = (ckp * 2 + 1) << 6, tend1 = tout1 + CHUNK_, ts1 = tout1 - WARM_;

  // ---- resident: wh (shared by both chunks) ----
  bf16x8 wh[8][4];
#pragma unroll
  for (int kt = 0; kt < 8; ++kt)
#pragma unroll
    for (int s = 0; s < 4; ++s) {
      ushort8 tmp;
#pragma unroll
      for (int j = 0; j < 8; ++j) {
        int k = kt * 32 + lq * 8 + j;
        int col = cg * 64 + s * 16 + lr;
        tmp[j] = f2bf(W[(size_t)(I_ + k) * H_ + col]);
      }
      wh[kt][s] = __builtin_bit_cast(bf16x8, tmp);
    }
#pragma unroll
  for (int kt = 0; kt < 2; ++kt)
#pragma unroll
    for (int s = 0; s < 4; ++s) {
      ushort8 tmp;
#pragma unroll
      for (int j = 0; j < 8; ++j) {
        int k = kt * 32 + lq * 8 + j;
        int col = cg * 64 + s * 16 + lr;
        tmp[j] = f2bf(W[(size_t)k * H_ + col]);
      }
      *(bf16x8*)(wxl + (((kt * 4 + s) * 4 + cg) * 64 + l) * 16) =
          __builtin_bit_cast(bf16x8, tmp);
    }
#pragma unroll
  for (int kt = 0; kt < 2; ++kt) {
    ushort8 tmp;
#pragma unroll
    for (int j = 0; j < 8; ++j) {
      int k = cg * 64 + kt * 32 + lq * 8 + j;
      tmp[j] = (lr < C_) ? f2bf(Wfc[(size_t)k * C_ + lr]) : (ushort_t)0;
    }
    *(bf16x8*)(wfl + ((kt * 4 + cg) * 64 + l) * 16) = __builtin_bit_cast(bf16x8, tmp);
  }
  if (tid < 64) *(float4*)(bhl + tid * 4) = *(const float4*)(bh + tid * 4);

  ((uint4*)hbuf0[0])[tid]       = (uint4){0, 0, 0, 0};
  ((uint4*)hbuf0[0])[tid + 256] = (uint4){0, 0, 0, 0};
  ((uint4*)hbuf1[0])[tid]       = (uint4){0, 0, 0, 0};
  ((uint4*)hbuf1[0])[tid + 256] = (uint4){0, 0, 0, 0};

  const int xrow = tid >> 4, xc = tid & 15;
  const float* xbase = x + (size_t)(b0 + xrow) * T_ * I_ + xc * 4;
  const int tf0 = (ts0 >= 0) ? ts0 : 0;  // first staged x for chunk0
  float4 xpre0 = *(const float4*)(xbase + (size_t)tf0 * I_);
  float4 xpre1 = *(const float4*)(xbase + (size_t)ts1 * I_);
  {
    int byte = xrow * 128 + xc * 8;
    byte ^= (xrow & 7) << 4;
    bf16x4 pk0 = {(__bf16)xpre0.x, (__bf16)xpre0.y, (__bf16)xpre0.z, (__bf16)xpre0.w};
    *(bf16x4*)(xls0 + byte) = pk0;
    bf16x4 pk1 = {(__bf16)xpre1.x, (__bf16)xpre1.y, (__bf16)xpre1.z, (__bf16)xpre1.w};
    *(bf16x4*)(xls1 + byte) = pk1;
  }
  __syncthreads();

  f32x4 xw0[4], xw1[4];
  const f32x4 zero4 = {0.f, 0.f, 0.f, 0.f};
  // xw for chunk c at its start (chunk0 of pair 0: forced zero -> h stays 0)
  if (ts0 >= 0) {
    bf16x8 xa[2];
#pragma unroll
    for (int kt = 0; kt < 2; ++kt) {
      int byte = lr * 128 + (kt * 32 + lq * 8) * 2;
      byte ^= (lr & 7) << 4;
      xa[kt] = *(const bf16x8*)(xls0 + byte);
    }
#pragma unroll
    for (int s = 0; s < 4; ++s) {
      float4 bi = *(const float4*)(bhl + cg * 64 + s * 16 + lq * 4);
      f32x4 a = (f32x4){bi.x, bi.y, bi.z, bi.w};
      bf16x8 w0 = *(const bf16x8*)(wxl + (((0 * 4 + s) * 4 + cg) * 64 + l) * 16);
      bf16x8 w1 = *(const bf16x8*)(wxl + (((1 * 4 + s) * 4 + cg) * 64 + l) * 16);
      a = MFMA(w0, xa[0], a);
      a = MFMA(w1, xa[1], a);
      xw0[s] = a;
    }
    xpre0 = *(const float4*)(xbase + (size_t)(ts0 + 1) * I_);
  } else {
#pragma unroll
    for (int s = 0; s < 4; ++s) xw0[s] = zero4;
    // xpre0 stays x(0) so the stage at tt0+1==0 writes x(0)
  }
  {
    bf16x8 xa[2];
#pragma unroll
    for (int kt = 0; kt < 2; ++kt) {
      int byte = lr * 128 + (kt * 32 + lq * 8) * 2;
      byte ^= (lr & 7) << 4;
      xa[kt] = *(const bf16x8*)(xls1 + byte);
    }
#pragma unroll
    for (int s = 0; s < 4; ++s) {
      float4 bi = *(const float4*)(bhl + cg * 64 + s * 16 + lq * 4);
      f32x4 a = (f32x4){bi.x, bi.y, bi.z, bi.w};
      bf16x8 w0 = *(const bf16x8*)(wxl + (((0 * 4 + s) * 4 + cg) * 64 + l) * 16);
      bf16x8 w1 = *(const bf16x8*)(wxl + (((1 * 4 + s) * 4 + cg) * 64 + l) * 16);
      a = MFMA(w0, xa[0], a);
      a = MFMA(w1, xa[1], a);
      xw1[s] = a;
    }
    xpre1 = *(const float4*)(xbase + (size_t)(ts1 + 1) * I_);
  }

  f32x4 h0[4], h1[4];
#pragma unroll
  for (int s = 0; s < 4; ++s) { h0[s] = zero4; h1[s] = zero4; }

  const bool ow = tid < 16 * C_;
  int or_ = 0, oc_ = 0;
  float bfc_r = 0.f;
  if (ow) { or_ = tid / C_; oc_ = tid - or_ * C_; bfc_r = bfc[oc_]; }

  const float TWO_LOG2E = 2.8853900817779268f;

#pragma unroll 1
  for (int i = 0; i < WARM_ + CHUNK_; ++i) {
    const int tt0 = ts0 + i;
    const int tt1 = ts1 + i;
#pragma unroll
    for (int u = 0; u < 6; ++u) {
      // ---------- chunk 0 ----------
      {
        const char* hb = hbuf0[u & 1];
        if (u == 0 && tt0 > tout0) {
          bf16x8 hA0, hA1, w0, w1;
          int byte = lr * 512 + ((2 * cg) * 32 + lq * 8) * 2;
          byte ^= (lr & 7) << 4;
          hA0 = *(const bf16x8*)(hb + byte);
          byte = lr * 512 + ((2 * cg + 1) * 32 + lq * 8) * 2;
          byte ^= (lr & 7) << 4;
          hA1 = *(const bf16x8*)(hb + byte);
          w0 = *(const bf16x8*)(wfl + ((0 * 4 + cg) * 64 + l) * 16);
          w1 = *(const bf16x8*)(wfl + ((1 * 4 + cg) * 64 + l) * 16);
          f32x4 part = zero4;
          part = MFMA(hA0, w0, part);
          part = MFMA(hA1, w1, part);
          if (lr < C_) {
#pragma unroll
            for (int jj = 0; jj < 4; ++jj) red0[cg][lq * 4 + jj][lr] = part[jj];
          }
        }
        f32x4 acc[4];
#pragma unroll
        for (int s = 0; s < 4; ++s) acc[s] = xw0[s];
        bf16x8 ha[8];
#pragma unroll
        for (int kt = 0; kt < 8; ++kt) {
          int byte = lr * 512 + (kt * 32 + lq * 8) * 2;
          byte ^= (lr & 7) << 4;
          ha[kt] = *(const bf16x8*)(hb + byte);
        }
#pragma unroll
        for (int kt = 0; kt < 8; ++kt)
#pragma unroll
          for (int s = 0; s < 4; ++s) acc[s] = MFMA(wh[kt][s], ha[kt], acc[s]);
        char* hw = hbuf0[(u + 1) & 1];
#pragma unroll
        for (int s = 0; s < 4; ++s) {
          f32x4 hv;
#pragma unroll
          for (int jj = 0; jj < 4; ++jj) {
            float v = acc[s][jj];
            float e = __builtin_amdgcn_exp2f(v * TWO_LOG2E);
            float r = __builtin_amdgcn_rcpf(e + 1.0f);
            float hn = __builtin_fmaf(-0.2f, r, __builtin_fmaf(0.9f, h0[s][jj], 0.1f));
            h0[s][jj] = hn;
            hv[jj] = hn;
          }
          int byte = lr * 512 + (cg * 128 + s * 32 + lq * 8);
          byte ^= (lr & 7) << 4;
          bf16x4 pk = {(__bf16)hv[0], (__bf16)hv[1], (__bf16)hv[2], (__bf16)hv[3]};
          *(bf16x4*)(hw + byte) = pk;
        }
        if (u == 5 && tt0 + 1 < tend0) {
          int byte = xrow * 128 + xc * 8;
          byte ^= (xrow & 7) << 4;
          bf16x4 pk = {(__bf16)xpre0.x, (__bf16)xpre0.y, (__bf16)xpre0.z, (__bf16)xpre0.w};
          *(bf16x4*)(xls0 + byte) = pk;
        }
      }
      // ---------- chunk 1 ----------
      {
        const char* hb = hbuf1[u & 1];
        if (u == 0 && tt1 > tout1) {
          bf16x8 hA0, hA1, w0, w1;
          int byte = lr * 512 + ((2 * cg) * 32 + lq * 8) * 2;
          byte ^= (lr & 7) << 4;
          hA0 = *(const bf16x8*)(hb + byte);
          byte = lr * 512 + ((2 * cg + 1) * 32 + lq * 8) * 2;
          byte ^= (lr & 7) << 4;
          hA1 = *(const bf16x8*)(hb + byte);
          w0 = *(const bf16x8*)(wfl + ((0 * 4 + cg) * 64 + l) * 16);
          w1 = *(const bf16x8*)(wfl + ((1 * 4 + cg) * 64 + l) * 16);
          f32x4 part = zero4;
          part = MFMA(hA0, w0, part);
          part = MFMA(hA1, w1, part);
          if (lr < C_) {
#pragma unroll
            for (int jj = 0; jj < 4; ++jj) red1[cg][lq * 4 + jj][lr] = part[jj];
          }
        }
        f32x4 acc[4];
#pragma unroll
        for (int s = 0; s < 4; ++s) acc[s] = xw1[s];
        bf16x8 ha[8];
#pragma unroll
        for (int kt = 0; kt < 8; ++kt) {
          int byte = lr * 512 + (kt * 32 + lq * 8) * 2;
          byte ^= (lr & 7) << 4;
          ha[kt] = *(const bf16x8*)(hb + byte);
        }
#pragma unroll
        for (int kt = 0; kt < 8; ++kt)
#pragma unroll
          for (int s = 0; s < 4; ++s) acc[s] = MFMA(wh[kt][s], ha[kt], acc[s]);
        char* hw = hbuf1[(u + 1) & 1];
#pragma unroll
        for (int s = 0; s < 4; ++s) {
          f32x4 hv;
#pragma unroll
          for (int jj = 0; jj < 4; ++jj) {
            float v = acc[s][jj];
            float e = __builtin_amdgcn_exp2f(v * TWO_LOG2E);
            float r = __builtin_amdgcn_rcpf(e + 1.0f);
            float hn = __builtin_fmaf(-0.2f, r, __builtin_fmaf(0.9f, h1[s][jj], 0.1f));
            h1[s][jj] = hn;
            hv[jj] = hn;
          }
          int byte = lr * 512 + (cg * 128 + s * 32 + lq * 8);
          byte ^= (lr & 7) << 4;
          bf16x4 pk = {(__bf16)hv[0], (__bf16)hv[1], (__bf16)hv[2], (__bf16)hv[3]};
          *(bf16x4*)(hw + byte) = pk;
        }
        if (u == 5 && tt1 + 1 < tend1) {
          int byte = xrow * 128 + xc * 8;
          byte ^= (xrow & 7) << 4;
          bf16x4 pk = {(__bf16)xpre1.x, (__bf16)xpre1.y, (__bf16)xpre1.z, (__bf16)xpre1.w};
          *(bf16x4*)(xls1 + byte) = pk;
        }
      }
      // logits stores at u==1 (red written before u==0's barrier)
      if (u == 1 && ow) {
        if (tt0 > tout0) {
          float sum = red0[0][or_][oc_] + red0[1][or_][oc_] + red0[2][or_][oc_] +
                      red0[3][or_][oc_] + bfc_r;
          out[((size_t)(b0 + or_) * C_ + oc_) * T_ + (tt0 - 1)] = sum;
        }
        if (tt1 > tout1) {
          float sum = red1[0][or_][oc_] + red1[1][or_][oc_] + red1[2][or_][oc_] +
                      red1[3][or_][oc_] + bfc_r;
          out[((size_t)(b0 + or_) * C_ + oc_) * T_ + (tt1 - 1)] = sum;
        }
      }
      bar_lds();
    }

    // ---------- xw(t+1) for both chunks ----------
    if (tt0 + 1 < tend0) {
      if (tt0 + 1 >= 0) {
        bf16x8 xa[2];
#pragma unroll
        for (int kt = 0; kt < 2; ++kt) {
          int byte = lr * 128 + (kt * 32 + lq * 8) * 2;
          byte ^= (lr & 7) << 4;
          xa[kt] = *(const bf16x8*)(xls0 + byte);
        }
#pragma unroll
        for (int s = 0; s < 4; ++s) {
          float4 bi = *(const float4*)(bhl + cg * 64 + s * 16 + lq * 4);
          f32x4 a = (f32x4){bi.x, bi.y, bi.z, bi.w};
          bf16x8 w0 = *(const bf16x8*)(wxl + (((0 * 4 + s) * 4 + cg) * 64 + l) * 16);
          bf16x8 w1 = *(const bf16x8*)(wxl + (((1 * 4 + s) * 4 + cg) * 64 + l) * 16);
          a = MFMA(w0, xa[0], a);
          a = MFMA(w1, xa[1], a);
          xw0[s] = a;
        }
      }
      if (tt0 + 2 >= 0 && tt0 + 2 < T_)
        xpre0 = *(const float4*)(xbase + (size_t)(tt0 + 2) * I_);
    }
    if (tt1 + 1 < tend1) {
      bf16x8 xa[2];
#pragma unroll
      for (int kt = 0; kt < 2; ++kt) {
        int byte = lr * 128 + (kt * 32 + lq * 8) * 2;
        byte ^= (lr & 7) << 4;
        xa[kt] = *(const bf16x8*)(xls1 + byte);
      }
#pragma unroll
      for (int s = 0; s < 4; ++s) {
        float4 bi = *(const float4*)(bhl + cg * 64 + s * 16 + lq * 4);
        f32x4 a = (f32x4){bi.x, bi.y, bi.z, bi.w};
        bf16x8 w0 = *(const bf16x8*)(wxl + (((0 * 4 + s) * 4 + cg) * 64 + l) * 16);
        bf16x8 w1 = *(const bf16x8*)(wxl + (((1 * 4 + s) * 4 + cg) * 64 + l) * 16);
        a = MFMA(w0, xa[0], a);
        a = MFMA(w1, xa[1], a);
        xw1[s] = a;
      }
      if (tt1 + 2 < T_)
        xpre1 = *(const float4*)(xbase + (size_t)(tt1 + 2) * I_);
    }
  }

  // ================= epilogue: logits(tend-1) both chunks =================
  {
    bf16x8 w0 = *(const bf16x8*)(wfl + ((0 * 4 + cg) * 64 + l) * 16);
    bf16x8 w1 = *(const bf16x8*)(wfl + ((1 * 4 + cg) * 64 + l) * 16);
    {
      const char* hb = hbuf0[0];
      bf16x8 hA0, hA1;
      int byte = lr * 512 + ((2 * cg) * 32 + lq * 8) * 2;
      byte ^= (lr & 7) << 4;
      hA0 = *(const bf16x8*)(hb + byte);
      byte = lr * 512 + ((2 * cg + 1) * 32 + lq * 8) * 2;
      byte ^= (lr & 7) << 4;
      hA1 = *(const bf16x8*)(hb + byte);
      f32x4 part = zero4;
      part = MFMA(hA0, w0, part);
      part = MFMA(hA1, w1, part);
      if (lr < C_) {
#pragma unroll
        for (int jj = 0; jj < 4; ++jj) red0[cg][lq * 4 + jj][lr] = part[jj];
      }
    }
    {
      const char* hb = hbuf1[0];
      bf16x8 hA0, hA1;
      int byte = lr * 512 + ((2 * cg) * 32 + lq * 8) * 2;
      byte ^= (lr & 7) << 4;
      hA0 = *(const bf16x8*)(hb + byte);
      byte = lr * 512 + ((2 * cg + 1) * 32 + lq * 8) * 2;
      byte ^= (lr & 7) << 4;
      hA1 = *(const bf16x8*)(hb + byte);
      f32x4 part = zero4;
      part = MFMA(hA0, w0, part);
      part = MFMA(hA1, w1, part);
      if (lr < C_) {
#pragma unroll
        for (int jj = 0; jj < 4; ++jj) red1[cg][lq * 4 + jj][lr] = part[jj];
      }
    }
  }
  bar_lds();
  if (ow) {
    float s0 = red0[0][or_][oc_] + red0[1][or_][oc_] + red0[2][or_][oc_] +
               red0[3][or_][oc_] + bfc_r;
    out[((size_t)(b0 + or_) * C_ + oc_) * T_ + (tend0 - 1)] = s0;
    float s1 = red1[0][or_][oc_] + red1[1][or_][oc_] + red1[2][or_][oc_] +
               red1[3][or_][oc_] + bfc_r;
    out[((size_t)(b0 + or_) * C_ + oc_) * T_ + (tend1 - 1)] = s1;
  }
}

extern "C" void kernel_launch(void* const* d_in, const int* in_sizes, int n_in,
                              void* d_out, int out_size, void* d_ws, size_t ws_size,
                              hipStream_t stream) {
  const float* x   = (const float*)d_in[0];
  const float* W   = (const float*)d_in[1];
  const float* bh  = (const float*)d_in[2];
  const float* Wfc = (const float*)d_in[3];
  const float* bfc = (const float*)d_in[4];
  float* out = (float*)d_out;
  (void)in_sizes; (void)n_in; (void)out_size; (void)d_ws; (void)ws_size;
  ctrnn_fused<<<dim3(256), dim3(256), 0, stream>>>(x, W, bh, Wfc, bfc, out);
}

// Round 18
// 549.031 us; speedup vs baseline: 8.0534x; 1.2920x over previous
//
#include <hip/hip_runtime.h>

// CTRNN fused, v14 = v11 + xw-phase folded into u5 (x staged at u4, xw
// recomputed in-place after its last use) + WARM 24->16.
// Resident: wh (128 AGPR); wx/wf/bias in LDS. Grid 512 (32 bg x 16 ck),
// 2 wgs/CU. WARM=16, CHUNK=64.

#define T_ 1024
#define I_ 64
#define H_ 256
#define C_ 5
#define WARM_ 16
#define CHUNK_ 64

typedef float f32x4 __attribute__((ext_vector_type(4)));
typedef __bf16 bf16x8 __attribute__((ext_vector_type(8)));
typedef __bf16 bf16x4 __attribute__((ext_vector_type(4)));
typedef unsigned short ushort_t;
typedef ushort_t ushort8 __attribute__((ext_vector_type(8)));

__device__ __forceinline__ ushort_t f2bf(float x) {  // setup only
  unsigned u = __builtin_bit_cast(unsigned, x);
  return (ushort_t)((u + 0x7FFFu + ((u >> 16) & 1u)) >> 16);
}
__device__ __forceinline__ void bar_lds() {
  __builtin_amdgcn_sched_barrier(0);
  asm volatile("s_waitcnt lgkmcnt(0)" ::: "memory");
  __builtin_amdgcn_s_barrier();
  __builtin_amdgcn_sched_barrier(0);
}
#define MFMA(a, b, c) __builtin_amdgcn_mfma_f32_16x16x32_bf16((a), (b), (c), 0, 0, 0)

__launch_bounds__(256, 2)
__global__ void ctrnn_fused(const float* __restrict__ x, const float* __restrict__ W,
                            const float* __restrict__ bh, const float* __restrict__ Wfc,
                            const float* __restrict__ bfc, float* __restrict__ out) {
  __shared__ __align__(16) char hbuf[2][16 * 256 * 2];  // swizzle byte^=(row&7)<<4
  __shared__ __align__(16) char xls[16 * 64 * 2];
  __shared__ __align__(16) char wxl[2 * 4 * 4 * 64 * 16];  // wx fragments, 32KB
  __shared__ __align__(16) char wfl[2 * 4 * 64 * 16];      // wf fragments, 8KB
  __shared__ __align__(16) float bhl[H_];                  // bias, 1KB
  __shared__ float red[4][16][C_];

  const int tid = threadIdx.x;
  const int cg  = tid >> 6;
  const int l   = tid & 63;
  const int lr  = l & 15;
  const int lq  = l >> 4;
  const int bg  = blockIdx.x & 31;   // batch group
  const int ck  = blockIdx.x >> 5;   // time chunk 0..15
  const int b0  = bg << 4;
  const int tout = ck << 6;                        // first output step
  const int t0   = (ck == 0) ? 0 : (tout - WARM_); // chain start (h=0 here)
  const int tend = tout + CHUNK_;

  // ---- resident: wh only (AGPR-eligible) ----
  bf16x8 wh[8][4];
#pragma unroll
  for (int kt = 0; kt < 8; ++kt)
#pragma unroll
    for (int s = 0; s < 4; ++s) {
      ushort8 tmp;
#pragma unroll
      for (int j = 0; j < 8; ++j) {
        int k = kt * 32 + lq * 8 + j;
        int col = cg * 64 + s * 16 + lr;
        tmp[j] = f2bf(W[(size_t)(I_ + k) * H_ + col]);
      }
      wh[kt][s] = __builtin_bit_cast(bf16x8, tmp);
    }
  // wx fragments -> LDS
#pragma unroll
  for (int kt = 0; kt < 2; ++kt)
#pragma unroll
    for (int s = 0; s < 4; ++s) {
      ushort8 tmp;
#pragma unroll
      for (int j = 0; j < 8; ++j) {
        int k = kt * 32 + lq * 8 + j;
        int col = cg * 64 + s * 16 + lr;
        tmp[j] = f2bf(W[(size_t)k * H_ + col]);
      }
      *(bf16x8*)(wxl + (((kt * 4 + s) * 4 + cg) * 64 + l) * 16) =
          __builtin_bit_cast(bf16x8, tmp);
    }
  // wf fragments -> LDS
#pragma unroll
  for (int kt = 0; kt < 2; ++kt) {
    ushort8 tmp;
#pragma unroll
    for (int j = 0; j < 8; ++j) {
      int k = cg * 64 + kt * 32 + lq * 8 + j;
      tmp[j] = (lr < C_) ? f2bf(Wfc[(size_t)k * C_ + lr]) : (ushort_t)0;
    }
    *(bf16x8*)(wfl + ((kt * 4 + cg) * 64 + l) * 16) = __builtin_bit_cast(bf16x8, tmp);
  }
  // bias -> LDS
  if (tid < 64) *(float4*)(bhl + tid * 4) = *(const float4*)(bh + tid * 4);

  ((uint4*)hbuf[0])[tid]       = (uint4){0, 0, 0, 0};
  ((uint4*)hbuf[0])[tid + 256] = (uint4){0, 0, 0, 0};

  const int xrow = tid >> 4, xc = tid & 15;
  const float* xbase = x + (size_t)(b0 + xrow) * T_ * I_ + xc * 4;
  float4 xpre = *(const float4*)(xbase + (size_t)t0 * I_);
  {
    int byte = xrow * 128 + xc * 8;
    byte ^= (xrow & 7) << 4;
    bf16x4 pk = {(__bf16)xpre.x, (__bf16)xpre.y, (__bf16)xpre.z, (__bf16)xpre.w};
    *(bf16x4*)(xls + byte) = pk;
  }
  __syncthreads();

  // xw(t0)
  f32x4 xw[4];
  {
    bf16x8 xa[2];
#pragma unroll
    for (int kt = 0; kt < 2; ++kt) {
      int byte = lr * 128 + (kt * 32 + lq * 8) * 2;
      byte ^= (lr & 7) << 4;
      xa[kt] = *(const bf16x8*)(xls + byte);
    }
    f32x4 a_[4];
#pragma unroll
    for (int s = 0; s < 4; ++s) {
      float4 bi = *(const float4*)(bhl + cg * 64 + s * 16 + lq * 4);
      a_[s] = (f32x4){bi.x, bi.y, bi.z, bi.w};
    }
#pragma unroll
    for (int kt = 0; kt < 2; ++kt) {
      bf16x8 wxr[4];
#pragma unroll
      for (int s = 0; s < 4; ++s)
        wxr[s] = *(const bf16x8*)(wxl + (((kt * 4 + s) * 4 + cg) * 64 + l) * 16);
#pragma unroll
      for (int s = 0; s < 4; ++s) a_[s] = MFMA(wxr[s], xa[kt], a_[s]);
    }
#pragma unroll
    for (int s = 0; s < 4; ++s) xw[s] = a_[s];
  }
  xpre = *(const float4*)(xbase + (size_t)(t0 + 1) * I_);  // x(t0+1)

  f32x4 h[4];
#pragma unroll
  for (int s = 0; s < 4; ++s) h[s] = (f32x4){0.f, 0.f, 0.f, 0.f};

  const bool ow = tid < 16 * C_;
  int or_ = 0, oc_ = 0;
  float bfc_r = 0.f;
  if (ow) { or_ = tid / C_; oc_ = tid - or_ * C_; bfc_r = bfc[oc_]; }

  const float TWO_LOG2E = 2.8853900817779268f;

#pragma unroll 1
  for (int tt = t0; tt < tend; ++tt) {
    // ================= u = 0 (peeled; + logits(tt-1) MFMA & red-write) ========
    {
      const char* hb = hbuf[0];
      if (tt > tout) {  // logits(tt-1): h(tt-1)-final == hbuf[0] right now
        bf16x8 hA0, hA1, wf0, wf1;
        int byte = lr * 512 + ((2 * cg) * 32 + lq * 8) * 2;
        byte ^= (lr & 7) << 4;
        hA0 = *(const bf16x8*)(hb + byte);
        byte = lr * 512 + ((2 * cg + 1) * 32 + lq * 8) * 2;
        byte ^= (lr & 7) << 4;
        hA1 = *(const bf16x8*)(hb + byte);
        wf0 = *(const bf16x8*)(wfl + ((0 * 4 + cg) * 64 + l) * 16);
        wf1 = *(const bf16x8*)(wfl + ((1 * 4 + cg) * 64 + l) * 16);
        f32x4 part = (f32x4){0.f, 0.f, 0.f, 0.f};
        part = MFMA(hA0, wf0, part);
        part = MFMA(hA1, wf1, part);
        if (lr < C_) {
#pragma unroll
          for (int jj = 0; jj < 4; ++jj) red[cg][lq * 4 + jj][lr] = part[jj];
        }
      }
      f32x4 acc[4];
#pragma unroll
      for (int s = 0; s < 4; ++s) acc[s] = xw[s];
      {
        bf16x8 ha[4];
#pragma unroll
        for (int kt = 0; kt < 4; ++kt) {
          int byte = lr * 512 + (kt * 32 + lq * 8) * 2;
          byte ^= (lr & 7) << 4;
          ha[kt] = *(const bf16x8*)(hb + byte);
        }
#pragma unroll
        for (int kt = 0; kt < 4; ++kt)
#pragma unroll
          for (int s = 0; s < 4; ++s) acc[s] = MFMA(wh[kt][s], ha[kt], acc[s]);
      }
      {
        bf16x8 ha[4];
#pragma unroll
        for (int kt = 0; kt < 4; ++kt) {
          int byte = lr * 512 + ((kt + 4) * 32 + lq * 8) * 2;
          byte ^= (lr & 7) << 4;
          ha[kt] = *(const bf16x8*)(hb + byte);
        }
#pragma unroll
        for (int kt = 0; kt < 4; ++kt)
#pragma unroll
          for (int s = 0; s < 4; ++s) acc[s] = MFMA(wh[kt + 4][s], ha[kt], acc[s]);
      }

      char* hw = hbuf[1];
#pragma unroll
      for (int s = 0; s < 4; ++s) {
        f32x4 hv;
#pragma unroll
        for (int jj = 0; jj < 4; ++jj) {
          float v = acc[s][jj];
          float e = __builtin_amdgcn_exp2f(v * TWO_LOG2E);
          float r = __builtin_amdgcn_rcpf(e + 1.0f);
          float hn = __builtin_fmaf(-0.2f, r, __builtin_fmaf(0.9f, h[s][jj], 0.1f));
          h[s][jj] = hn;
          hv[jj] = hn;
        }
        int byte = lr * 512 + (cg * 128 + s * 32 + lq * 8);
        byte ^= (lr & 7) << 4;
        bf16x4 pk = {(__bf16)hv[0], (__bf16)hv[1], (__bf16)hv[2], (__bf16)hv[3]};
        *(bf16x4*)(hw + byte) = pk;
      }
      bar_lds();
    }

    // ================= u = 1..5 =================
#pragma unroll
    for (int u = 1; u < 6; ++u) {
      const char* hb = hbuf[u & 1];
      f32x4 acc[4];
#pragma unroll
      for (int s = 0; s < 4; ++s) acc[s] = xw[s];
      {
        bf16x8 ha[4];
#pragma unroll
        for (int kt = 0; kt < 4; ++kt) {
          int byte = lr * 512 + (kt * 32 + lq * 8) * 2;
          byte ^= (lr & 7) << 4;
          ha[kt] = *(const bf16x8*)(hb + byte);
        }
#pragma unroll
        for (int kt = 0; kt < 4; ++kt)
#pragma unroll
          for (int s = 0; s < 4; ++s) acc[s] = MFMA(wh[kt][s], ha[kt], acc[s]);
      }
      {
        bf16x8 ha[4];
#pragma unroll
        for (int kt = 0; kt < 4; ++kt) {
          int byte = lr * 512 + ((kt + 4) * 32 + lq * 8) * 2;
          byte ^= (lr & 7) << 4;
          ha[kt] = *(const bf16x8*)(hb + byte);
        }
#pragma unroll
        for (int kt = 0; kt < 4; ++kt)
#pragma unroll
          for (int s = 0; s < 4; ++s) acc[s] = MFMA(wh[kt + 4][s], ha[kt], acc[s]);
      }

      if (u == 1 && tt > tout && ow) {  // store logits(tt-1)
        float sum = red[0][or_][oc_] + red[1][or_][oc_] + red[2][or_][oc_] +
                    red[3][or_][oc_] + bfc_r;
        out[((size_t)(b0 + or_) * C_ + oc_) * T_ + (tt - 1)] = sum;
      }

      // u=5: xw(tt+1) recomputed in place (xw last used at acc init above);
      // x(tt+1) was staged into xls at u=4 (visible after u4's barrier).
      if (u == 5 && tt + 1 < tend) {
        bf16x8 xa[2];
#pragma unroll
        for (int kt = 0; kt < 2; ++kt) {
          int byte = lr * 128 + (kt * 32 + lq * 8) * 2;
          byte ^= (lr & 7) << 4;
          xa[kt] = *(const bf16x8*)(xls + byte);
        }
        f32x4 a_[4];
#pragma unroll
        for (int s = 0; s < 4; ++s) {
          float4 bi = *(const float4*)(bhl + cg * 64 + s * 16 + lq * 4);
          a_[s] = (f32x4){bi.x, bi.y, bi.z, bi.w};
        }
#pragma unroll
        for (int kt = 0; kt < 2; ++kt) {
          bf16x8 wxr[4];
#pragma unroll
          for (int s = 0; s < 4; ++s)
            wxr[s] = *(const bf16x8*)(wxl + (((kt * 4 + s) * 4 + cg) * 64 + l) * 16);
#pragma unroll
          for (int s = 0; s < 4; ++s) a_[s] = MFMA(wxr[s], xa[kt], a_[s]);
        }
#pragma unroll
        for (int s = 0; s < 4; ++s) xw[s] = a_[s];
      }

      char* hw = hbuf[(u + 1) & 1];
#pragma unroll
      for (int s = 0; s < 4; ++s) {
        f32x4 hv;
#pragma unroll
        for (int jj = 0; jj < 4; ++jj) {
          float v = acc[s][jj];
          float e = __builtin_amdgcn_exp2f(v * TWO_LOG2E);
          float r = __builtin_amdgcn_rcpf(e + 1.0f);
          float hn = __builtin_fmaf(-0.2f, r, __builtin_fmaf(0.9f, h[s][jj], 0.1f));
          h[s][jj] = hn;
          hv[jj] = hn;
        }
        int byte = lr * 512 + (cg * 128 + s * 32 + lq * 8);
        byte ^= (lr & 7) << 4;
        bf16x4 pk = {(__bf16)hv[0], (__bf16)hv[1], (__bf16)hv[2], (__bf16)hv[3]};
        *(bf16x4*)(hw + byte) = pk;
      }
      if (u == 4 && tt + 1 < tend) {  // stage x(tt+1), rides u4's barrier
        int byte = xrow * 128 + xc * 8;
        byte ^= (xrow & 7) << 4;
        bf16x4 pk = {(__bf16)xpre.x, (__bf16)xpre.y, (__bf16)xpre.z, (__bf16)xpre.w};
        *(bf16x4*)(xls + byte) = pk;
      }
      if (u == 5 && tt + 2 < T_ && tt + 1 < tend)  // prefetch x(tt+2)
        xpre = *(const float4*)(xbase + (size_t)(tt + 2) * I_);
      bar_lds();
    }
  }

  // ================= epilogue: logits(tend-1) =================
  {
    const char* hb = hbuf[0];
    bf16x8 hA0, hA1, wf0, wf1;
    int byte = lr * 512 + ((2 * cg) * 32 + lq * 8) * 2;
    byte ^= (lr & 7) << 4;
    hA0 = *(const bf16x8*)(hb + byte);
    byte = lr * 512 + ((2 * cg + 1) * 32 + lq * 8) * 2;
    byte ^= (lr & 7) << 4;
    hA1 = *(const bf16x8*)(hb + byte);
    wf0 = *(const bf16x8*)(wfl + ((0 * 4 + cg) * 64 + l) * 16);
    wf1 = *(const bf16x8*)(wfl + ((1 * 4 + cg) * 64 + l) * 16);
    f32x4 part = (f32x4){0.f, 0.f, 0.f, 0.f};
    part = MFMA(hA0, wf0, part);
    part = MFMA(hA1, wf1, part);
    if (lr < C_) {
#pragma unroll
      for (int jj = 0; jj < 4; ++jj) red[cg][lq * 4 + jj][lr] = part[jj];
    }
  }
  bar_lds();
  if (ow) {
    float sum = red[0][or_][oc_] + red[1][or_][oc_] + red[2][or_][oc_] +
                red[3][or_][oc_] + bfc_r;
    out[((size_t)(b0 + or_) * C_ + oc_) * T_ + (tend - 1)] = sum;
  }
}

extern "C" void kernel_launch(void* const* d_in, const int* in_sizes, int n_in,
                              void* d_out, int out_size, void* d_ws, size_t ws_size,
                              hipStream_t stream) {
  const float* x   = (const float*)d_in[0];
  const float* W   = (const float*)d_in[1];
  const float* bh  = (const float*)d_in[2];
  const float* Wfc = (const float*)d_in[3];
  const float* bfc = (const float*)d_in[4];
  float* out = (float*)d_out;
  (void)in_sizes; (void)n_in; (void)out_size; (void)d_ws; (void)ws_size;
  ctrnn_fused<<<dim3(512), dim3(256), 0, stream>>>(x, W, bh, Wfc, bfc, out);
}

// Round 19
// 540.806 us; speedup vs baseline: 8.1759x; 1.0152x over previous
//
#include <hip/hip_runtime.h>

// CTRNN fused, v15 = v14 + hbuf re-layout [kt:8][row:16][32elem=64B], swizzle
// byte ^= ((row>>1)&3)<<4. Reads: 8 lanes/4-bank window = 8clk (structural min,
// was 16 — old layout's lr*512 confined reads to one 16-bank half). Writes:
// 4 lanes/2-bank window = 4clk (min). kt-stride 1024 disjoint from swizzle bits
// -> base + immediate addressing, no per-access XOR math.
// Resident: wh (128 AGPR); wx/wf/bias in LDS. Grid 512, 2 wgs/CU. WARM=16.

#define T_ 1024
#define I_ 64
#define H_ 256
#define C_ 5
#define WARM_ 16
#define CHUNK_ 64

typedef float f32x4 __attribute__((ext_vector_type(4)));
typedef __bf16 bf16x8 __attribute__((ext_vector_type(8)));
typedef __bf16 bf16x4 __attribute__((ext_vector_type(4)));
typedef unsigned short ushort_t;
typedef ushort_t ushort8 __attribute__((ext_vector_type(8)));

__device__ __forceinline__ ushort_t f2bf(float x) {  // setup only
  unsigned u = __builtin_bit_cast(unsigned, x);
  return (ushort_t)((u + 0x7FFFu + ((u >> 16) & 1u)) >> 16);
}
__device__ __forceinline__ void bar_lds() {
  __builtin_amdgcn_sched_barrier(0);
  asm volatile("s_waitcnt lgkmcnt(0)" ::: "memory");
  __builtin_amdgcn_s_barrier();
  __builtin_amdgcn_sched_barrier(0);
}
#define MFMA(a, b, c) __builtin_amdgcn_mfma_f32_16x16x32_bf16((a), (b), (c), 0, 0, 0)

__launch_bounds__(256, 2)
__global__ void ctrnn_fused(const float* __restrict__ x, const float* __restrict__ W,
                            const float* __restrict__ bh, const float* __restrict__ Wfc,
                            const float* __restrict__ bfc, float* __restrict__ out) {
  // h ping-pong: [parity][kt:8][row:16][64B]  (8KB per parity)
  __shared__ __align__(16) char hbuf[2][8 * 16 * 64];
  __shared__ __align__(16) char xls[16 * 64 * 2];
  __shared__ __align__(16) char wxl[2 * 4 * 4 * 64 * 16];  // wx fragments, 32KB
  __shared__ __align__(16) char wfl[2 * 4 * 64 * 16];      // wf fragments, 8KB
  __shared__ __align__(16) float bhl[H_];                  // bias, 1KB
  __shared__ float red[4][16][C_];

  const int tid = threadIdx.x;
  const int cg  = tid >> 6;
  const int l   = tid & 63;
  const int lr  = l & 15;
  const int lq  = l >> 4;
  const int bg  = blockIdx.x & 31;   // batch group
  const int ck  = blockIdx.x >> 5;   // time chunk 0..15
  const int b0  = bg << 4;
  const int tout = ck << 6;
  const int t0   = (ck == 0) ? 0 : (tout - WARM_);
  const int tend = tout + CHUNK_;

  // lane-constant LDS addressing for hbuf
  const int swzb  = ((lr >> 1) & 3) << 4;
  const int rbase = (lr * 64 + lq * 16) ^ swzb;  // + kt*1024 (immediate)

  // ---- resident: wh only (AGPR-eligible) ----
  bf16x8 wh[8][4];
#pragma unroll
  for (int kt = 0; kt < 8; ++kt)
#pragma unroll
    for (int s = 0; s < 4; ++s) {
      ushort8 tmp;
#pragma unroll
      for (int j = 0; j < 8; ++j) {
        int k = kt * 32 + lq * 8 + j;
        int col = cg * 64 + s * 16 + lr;
        tmp[j] = f2bf(W[(size_t)(I_ + k) * H_ + col]);
      }
      wh[kt][s] = __builtin_bit_cast(bf16x8, tmp);
    }
  // wx fragments -> LDS
#pragma unroll
  for (int kt = 0; kt < 2; ++kt)
#pragma unroll
    for (int s = 0; s < 4; ++s) {
      ushort8 tmp;
#pragma unroll
      for (int j = 0; j < 8; ++j) {
        int k = kt * 32 + lq * 8 + j;
        int col = cg * 64 + s * 16 + lr;
        tmp[j] = f2bf(W[(size_t)k * H_ + col]);
      }
      *(bf16x8*)(wxl + (((kt * 4 + s) * 4 + cg) * 64 + l) * 16) =
          __builtin_bit_cast(bf16x8, tmp);
    }
  // wf fragments -> LDS
#pragma unroll
  for (int kt = 0; kt < 2; ++kt) {
    ushort8 tmp;
#pragma unroll
    for (int j = 0; j < 8; ++j) {
      int k = cg * 64 + kt * 32 + lq * 8 + j;
      tmp[j] = (lr < C_) ? f2bf(Wfc[(size_t)k * C_ + lr]) : (ushort_t)0;
    }
    *(bf16x8*)(wfl + ((kt * 4 + cg) * 64 + l) * 16) = __builtin_bit_cast(bf16x8, tmp);
  }
  // bias -> LDS
  if (tid < 64) *(float4*)(bhl + tid * 4) = *(const float4*)(bh + tid * 4);

  // zero h(-1) parity 0 (8KB, layout-agnostic)
  ((uint4*)hbuf[0])[tid]       = (uint4){0, 0, 0, 0};
  ((uint4*)hbuf[0])[tid + 256] = (uint4){0, 0, 0, 0};

  const int xrow = tid >> 4, xc = tid & 15;
  const float* xbase = x + (size_t)(b0 + xrow) * T_ * I_ + xc * 4;
  float4 xpre = *(const float4*)(xbase + (size_t)t0 * I_);
  {
    int byte = xrow * 128 + xc * 8;
    byte ^= (xrow & 7) << 4;
    bf16x4 pk = {(__bf16)xpre.x, (__bf16)xpre.y, (__bf16)xpre.z, (__bf16)xpre.w};
    *(bf16x4*)(xls + byte) = pk;
  }
  __syncthreads();

  // xw(t0)
  f32x4 xw[4];
  {
    bf16x8 xa[2];
#pragma unroll
    for (int kt = 0; kt < 2; ++kt) {
      int byte = lr * 128 + (kt * 32 + lq * 8) * 2;
      byte ^= (lr & 7) << 4;
      xa[kt] = *(const bf16x8*)(xls + byte);
    }
    f32x4 a_[4];
#pragma unroll
    for (int s = 0; s < 4; ++s) {
      float4 bi = *(const float4*)(bhl + cg * 64 + s * 16 + lq * 4);
      a_[s] = (f32x4){bi.x, bi.y, bi.z, bi.w};
    }
#pragma unroll
    for (int kt = 0; kt < 2; ++kt) {
      bf16x8 wxr[4];
#pragma unroll
      for (int s = 0; s < 4; ++s)
        wxr[s] = *(const bf16x8*)(wxl + (((kt * 4 + s) * 4 + cg) * 64 + l) * 16);
#pragma unroll
      for (int s = 0; s < 4; ++s) a_[s] = MFMA(wxr[s], xa[kt], a_[s]);
    }
#pragma unroll
    for (int s = 0; s < 4; ++s) xw[s] = a_[s];
  }
  xpre = *(const float4*)(xbase + (size_t)(t0 + 1) * I_);

  f32x4 h[4];
#pragma unroll
  for (int s = 0; s < 4; ++s) h[s] = (f32x4){0.f, 0.f, 0.f, 0.f};

  const bool ow = tid < 16 * C_;
  int or_ = 0, oc_ = 0;
  float bfc_r = 0.f;
  if (ow) { or_ = tid / C_; oc_ = tid - or_ * C_; bfc_r = bfc[oc_]; }

  const float TWO_LOG2E = 2.8853900817779268f;

#pragma unroll 1
  for (int tt = t0; tt < tend; ++tt) {
    // ================= u = 0 (peeled; + logits(tt-1)) ========
    {
      const char* hb = hbuf[0];
      if (tt > tout) {  // logits(tt-1): h(tt-1)-final == hbuf[0]
        bf16x8 hA0 = *(const bf16x8*)(hb + rbase + (2 * cg) * 1024);
        bf16x8 hA1 = *(const bf16x8*)(hb + rbase + (2 * cg + 1) * 1024);
        bf16x8 wf0 = *(const bf16x8*)(wfl + ((0 * 4 + cg) * 64 + l) * 16);
        bf16x8 wf1 = *(const bf16x8*)(wfl + ((1 * 4 + cg) * 64 + l) * 16);
        f32x4 part = (f32x4){0.f, 0.f, 0.f, 0.f};
        part = MFMA(hA0, wf0, part);
        part = MFMA(hA1, wf1, part);
        if (lr < C_) {
#pragma unroll
          for (int jj = 0; jj < 4; ++jj) red[cg][lq * 4 + jj][lr] = part[jj];
        }
      }
      f32x4 acc[4];
#pragma unroll
      for (int s = 0; s < 4; ++s) acc[s] = xw[s];
      {
        bf16x8 ha[4];
#pragma unroll
        for (int kt = 0; kt < 4; ++kt)
          ha[kt] = *(const bf16x8*)(hb + rbase + kt * 1024);
#pragma unroll
        for (int kt = 0; kt < 4; ++kt)
#pragma unroll
          for (int s = 0; s < 4; ++s) acc[s] = MFMA(wh[kt][s], ha[kt], acc[s]);
      }
      {
        bf16x8 ha[4];
#pragma unroll
        for (int kt = 0; kt < 4; ++kt)
          ha[kt] = *(const bf16x8*)(hb + rbase + (kt + 4) * 1024);
#pragma unroll
        for (int kt = 0; kt < 4; ++kt)
#pragma unroll
          for (int s = 0; s < 4; ++s) acc[s] = MFMA(wh[kt + 4][s], ha[kt], acc[s]);
      }

      char* hw = hbuf[1];
#pragma unroll
      for (int s = 0; s < 4; ++s) {
        f32x4 hv;
#pragma unroll
        for (int jj = 0; jj < 4; ++jj) {
          float v = acc[s][jj];
          float e = __builtin_amdgcn_exp2f(v * TWO_LOG2E);
          float r = __builtin_amdgcn_rcpf(e + 1.0f);
          float hn = __builtin_fmaf(-0.2f, r, __builtin_fmaf(0.9f, h[s][jj], 0.1f));
          h[s][jj] = hn;
          hv[jj] = hn;
        }
        int byte = (cg * 2 + (s >> 1)) * 1024 + lr * 64 +
                   ((((s & 1) * 32) + lq * 8) ^ swzb);
        bf16x4 pk = {(__bf16)hv[0], (__bf16)hv[1], (__bf16)hv[2], (__bf16)hv[3]};
        *(bf16x4*)(hw + byte) = pk;
      }
      bar_lds();
    }

    // ================= u = 1..5 =================
#pragma unroll
    for (int u = 1; u < 6; ++u) {
      const char* hb = hbuf[u & 1];
      f32x4 acc[4];
#pragma unroll
      for (int s = 0; s < 4; ++s) acc[s] = xw[s];
      {
        bf16x8 ha[4];
#pragma unroll
        for (int kt = 0; kt < 4; ++kt)
          ha[kt] = *(const bf16x8*)(hb + rbase + kt * 1024);
#pragma unroll
        for (int kt = 0; kt < 4; ++kt)
#pragma unroll
          for (int s = 0; s < 4; ++s) acc[s] = MFMA(wh[kt][s], ha[kt], acc[s]);
      }
      {
        bf16x8 ha[4];
#pragma unroll
        for (int kt = 0; kt < 4; ++kt)
          ha[kt] = *(const bf16x8*)(hb + rbase + (kt + 4) * 1024);
#pragma unroll
        for (int kt = 0; kt < 4; ++kt)
#pragma unroll
          for (int s = 0; s < 4; ++s) acc[s] = MFMA(wh[kt + 4][s], ha[kt], acc[s]);
      }

      if (u == 1 && tt > tout && ow) {  // store logits(tt-1)
        float sum = red[0][or_][oc_] + red[1][or_][oc_] + red[2][or_][oc_] +
                    red[3][or_][oc_] + bfc_r;
        out[((size_t)(b0 + or_) * C_ + oc_) * T_ + (tt - 1)] = sum;
      }

      // u=5: xw(tt+1) recomputed in place (x staged at u=4)
      if (u == 5 && tt + 1 < tend) {
        bf16x8 xa[2];
#pragma unroll
        for (int kt = 0; kt < 2; ++kt) {
          int byte = lr * 128 + (kt * 32 + lq * 8) * 2;
          byte ^= (lr & 7) << 4;
          xa[kt] = *(const bf16x8*)(xls + byte);
        }
        f32x4 a_[4];
#pragma unroll
        for (int s = 0; s < 4; ++s) {
          float4 bi = *(const float4*)(bhl + cg * 64 + s * 16 + lq * 4);
          a_[s] = (f32x4){bi.x, bi.y, bi.z, bi.w};
        }
#pragma unroll
        for (int kt = 0; kt < 2; ++kt) {
          bf16x8 wxr[4];
#pragma unroll
          for (int s = 0; s < 4; ++s)
            wxr[s] = *(const bf16x8*)(wxl + (((kt * 4 + s) * 4 + cg) * 64 + l) * 16);
#pragma unroll
          for (int s = 0; s < 4; ++s) a_[s] = MFMA(wxr[s], xa[kt], a_[s]);
        }
#pragma unroll
        for (int s = 0; s < 4; ++s) xw[s] = a_[s];
      }

      char* hw = hbuf[(u + 1) & 1];
#pragma unroll
      for (int s = 0; s < 4; ++s) {
        f32x4 hv;
#pragma unroll
        for (int jj = 0; jj < 4; ++jj) {
          float v = acc[s][jj];
          float e = __builtin_amdgcn_exp2f(v * TWO_LOG2E);
          float r = __builtin_amdgcn_rcpf(e + 1.0f);
          float hn = __builtin_fmaf(-0.2f, r, __builtin_fmaf(0.9f, h[s][jj], 0.1f));
          h[s][jj] = hn;
          hv[jj] = hn;
        }
        int byte = (cg * 2 + (s >> 1)) * 1024 + lr * 64 +
                   ((((s & 1) * 32) + lq * 8) ^ swzb);
        bf16x4 pk = {(__bf16)hv[0], (__bf16)hv[1], (__bf16)hv[2], (__bf16)hv[3]};
        *(bf16x4*)(hw + byte) = pk;
      }
      if (u == 4 && tt + 1 < tend) {  // stage x(tt+1), rides u4's barrier
        int byte = xrow * 128 + xc * 8;
        byte ^= (xrow & 7) << 4;
        bf16x4 pk = {(__bf16)xpre.x, (__bf16)xpre.y, (__bf16)xpre.z, (__bf16)xpre.w};
        *(bf16x4*)(xls + byte) = pk;
      }
      if (u == 5 && tt + 2 < T_ && tt + 1 < tend)  // prefetch x(tt+2)
        xpre = *(const float4*)(xbase + (size_t)(tt + 2) * I_);
      bar_lds();
    }
  }

  // ================= epilogue: logits(tend-1) =================
  {
    const char* hb = hbuf[0];
    bf16x8 hA0 = *(const bf16x8*)(hb + rbase + (2 * cg) * 1024);
    bf16x8 hA1 = *(const bf16x8*)(hb + rbase + (2 * cg + 1) * 1024);
    bf16x8 wf0 = *(const bf16x8*)(wfl + ((0 * 4 + cg) * 64 + l) * 16);
    bf16x8 wf1 = *(const bf16x8*)(wfl + ((1 * 4 + cg) * 64 + l) * 16);
    f32x4 part = (f32x4){0.f, 0.f, 0.f, 0.f};
    part = MFMA(hA0, wf0, part);
    part = MFMA(hA1, wf1, part);
    if (lr < C_) {
#pragma unroll
      for (int jj = 0; jj < 4; ++jj) red[cg][lq * 4 + jj][lr] = part[jj];
    }
  }
  bar_lds();
  if (ow) {
    float sum = red[0][or_][oc_] + red[1][or_][oc_] + red[2][or_][oc_] +
                red[3][or_][oc_] + bfc_r;
    out[((size_t)(b0 + or_) * C_ + oc_) * T_ + (tend - 1)] = sum;
  }
}

extern "C" void kernel_launch(void* const* d_in, const int* in_sizes, int n_in,
                              void* d_out, int out_size, void* d_ws, size_t ws_size,
                              hipStream_t stream) {
  const float* x   = (const float*)d_in[0];
  const float* W   = (const float*)d_in[1];
  const float* bh  = (const float*)d_in[2];
  const float* Wfc = (const float*)d_in[3];
  const float* bfc = (const float*)d_in[4];
  float* out = (float*)d_out;
  (void)in_sizes; (void)n_in; (void)out_size; (void)d_ws; (void)ws_size;
  ctrnn_fused<<<dim3(512), dim3(256), 0, stream>>>(x, W, bh, Wfc, bfc, out);
}

// Round 20
// 525.776 us; speedup vs baseline: 8.4096x; 1.0286x over previous
//
#include <hip/hip_runtime.h>

// CTRNN fused, v16 = v15 + s-pair software pipeline inside each unfold:
// MFMA s{0,1} -> tanh+write s{0,1} -> MFMA s{2,3} -> tanh+write s{2,3}.
// tanh(s01) is independent of MFMA(s23) -> scheduler interleaves; exposed
// tanh tail halves. Layout/sync/numerics identical to v15.
// Resident: wh (128 AGPR); wx/wf/bias in LDS. Grid 512, 2 wgs/CU. WARM=16.

#define T_ 1024
#define I_ 64
#define H_ 256
#define C_ 5
#define WARM_ 16
#define CHUNK_ 64

typedef float f32x4 __attribute__((ext_vector_type(4)));
typedef __bf16 bf16x8 __attribute__((ext_vector_type(8)));
typedef __bf16 bf16x4 __attribute__((ext_vector_type(4)));
typedef unsigned short ushort_t;
typedef ushort_t ushort8 __attribute__((ext_vector_type(8)));

__device__ __forceinline__ ushort_t f2bf(float x) {  // setup only
  unsigned u = __builtin_bit_cast(unsigned, x);
  return (ushort_t)((u + 0x7FFFu + ((u >> 16) & 1u)) >> 16);
}
__device__ __forceinline__ void bar_lds() {
  __builtin_amdgcn_sched_barrier(0);
  asm volatile("s_waitcnt lgkmcnt(0)" ::: "memory");
  __builtin_amdgcn_s_barrier();
  __builtin_amdgcn_sched_barrier(0);
}
#define MFMA(a, b, c) __builtin_amdgcn_mfma_f32_16x16x32_bf16((a), (b), (c), 0, 0, 0)

__launch_bounds__(256, 2)
__global__ void ctrnn_fused(const float* __restrict__ x, const float* __restrict__ W,
                            const float* __restrict__ bh, const float* __restrict__ Wfc,
                            const float* __restrict__ bfc, float* __restrict__ out) {
  // h ping-pong: [parity][kt:8][row:16][64B]  (8KB per parity)
  __shared__ __align__(16) char hbuf[2][8 * 16 * 64];
  __shared__ __align__(16) char xls[16 * 64 * 2];
  __shared__ __align__(16) char wxl[2 * 4 * 4 * 64 * 16];  // wx fragments, 32KB
  __shared__ __align__(16) char wfl[2 * 4 * 64 * 16];      // wf fragments, 8KB
  __shared__ __align__(16) float bhl[H_];                  // bias, 1KB
  __shared__ float red[4][16][C_];

  const int tid = threadIdx.x;
  const int cg  = tid >> 6;
  const int l   = tid & 63;
  const int lr  = l & 15;
  const int lq  = l >> 4;
  const int bg  = blockIdx.x & 31;   // batch group
  const int ck  = blockIdx.x >> 5;   // time chunk 0..15
  const int b0  = bg << 4;
  const int tout = ck << 6;
  const int t0   = (ck == 0) ? 0 : (tout - WARM_);
  const int tend = tout + CHUNK_;

  // lane-constant LDS addressing for hbuf
  const int swzb  = ((lr >> 1) & 3) << 4;
  const int rbase = (lr * 64 + lq * 16) ^ swzb;  // + kt*1024 (immediate)

  // ---- resident: wh only (AGPR-eligible) ----
  bf16x8 wh[8][4];
#pragma unroll
  for (int kt = 0; kt < 8; ++kt)
#pragma unroll
    for (int s = 0; s < 4; ++s) {
      ushort8 tmp;
#pragma unroll
      for (int j = 0; j < 8; ++j) {
        int k = kt * 32 + lq * 8 + j;
        int col = cg * 64 + s * 16 + lr;
        tmp[j] = f2bf(W[(size_t)(I_ + k) * H_ + col]);
      }
      wh[kt][s] = __builtin_bit_cast(bf16x8, tmp);
    }
  // wx fragments -> LDS
#pragma unroll
  for (int kt = 0; kt < 2; ++kt)
#pragma unroll
    for (int s = 0; s < 4; ++s) {
      ushort8 tmp;
#pragma unroll
      for (int j = 0; j < 8; ++j) {
        int k = kt * 32 + lq * 8 + j;
        int col = cg * 64 + s * 16 + lr;
        tmp[j] = f2bf(W[(size_t)k * H_ + col]);
      }
      *(bf16x8*)(wxl + (((kt * 4 + s) * 4 + cg) * 64 + l) * 16) =
          __builtin_bit_cast(bf16x8, tmp);
    }
  // wf fragments -> LDS
#pragma unroll
  for (int kt = 0; kt < 2; ++kt) {
    ushort8 tmp;
#pragma unroll
    for (int j = 0; j < 8; ++j) {
      int k = cg * 64 + kt * 32 + lq * 8 + j;
      tmp[j] = (lr < C_) ? f2bf(Wfc[(size_t)k * C_ + lr]) : (ushort_t)0;
    }
    *(bf16x8*)(wfl + ((kt * 4 + cg) * 64 + l) * 16) = __builtin_bit_cast(bf16x8, tmp);
  }
  // bias -> LDS
  if (tid < 64) *(float4*)(bhl + tid * 4) = *(const float4*)(bh + tid * 4);

  // zero h(-1) parity 0
  ((uint4*)hbuf[0])[tid]       = (uint4){0, 0, 0, 0};
  ((uint4*)hbuf[0])[tid + 256] = (uint4){0, 0, 0, 0};

  const int xrow = tid >> 4, xc = tid & 15;
  const float* xbase = x + (size_t)(b0 + xrow) * T_ * I_ + xc * 4;
  float4 xpre = *(const float4*)(xbase + (size_t)t0 * I_);
  {
    int byte = xrow * 128 + xc * 8;
    byte ^= (xrow & 7) << 4;
    bf16x4 pk = {(__bf16)xpre.x, (__bf16)xpre.y, (__bf16)xpre.z, (__bf16)xpre.w};
    *(bf16x4*)(xls + byte) = pk;
  }
  __syncthreads();

  // xw(t0)
  f32x4 xw[4];
  {
    bf16x8 xa[2];
#pragma unroll
    for (int kt = 0; kt < 2; ++kt) {
      int byte = lr * 128 + (kt * 32 + lq * 8) * 2;
      byte ^= (lr & 7) << 4;
      xa[kt] = *(const bf16x8*)(xls + byte);
    }
    f32x4 a_[4];
#pragma unroll
    for (int s = 0; s < 4; ++s) {
      float4 bi = *(const float4*)(bhl + cg * 64 + s * 16 + lq * 4);
      a_[s] = (f32x4){bi.x, bi.y, bi.z, bi.w};
    }
#pragma unroll
    for (int kt = 0; kt < 2; ++kt) {
      bf16x8 wxr[4];
#pragma unroll
      for (int s = 0; s < 4; ++s)
        wxr[s] = *(const bf16x8*)(wxl + (((kt * 4 + s) * 4 + cg) * 64 + l) * 16);
#pragma unroll
      for (int s = 0; s < 4; ++s) a_[s] = MFMA(wxr[s], xa[kt], a_[s]);
    }
#pragma unroll
    for (int s = 0; s < 4; ++s) xw[s] = a_[s];
  }
  xpre = *(const float4*)(xbase + (size_t)(t0 + 1) * I_);

  f32x4 h[4];
#pragma unroll
  for (int s = 0; s < 4; ++s) h[s] = (f32x4){0.f, 0.f, 0.f, 0.f};

  const bool ow = tid < 16 * C_;
  int or_ = 0, oc_ = 0;
  float bfc_r = 0.f;
  if (ow) { or_ = tid / C_; oc_ = tid - or_ * C_; bfc_r = bfc[oc_]; }

  const float TWO_LOG2E = 2.8853900817779268f;

#pragma unroll 1
  for (int tt = t0; tt < tend; ++tt) {
#pragma unroll
    for (int u = 0; u < 6; ++u) {
      const char* hb = hbuf[u & 1];
      char* hw = hbuf[(u + 1) & 1];

      // u=0: logits(tt-1) (h(tt-1)-final == hbuf[0] right now)
      if (u == 0 && tt > tout) {
        bf16x8 hA0 = *(const bf16x8*)(hb + rbase + (2 * cg) * 1024);
        bf16x8 hA1 = *(const bf16x8*)(hb + rbase + (2 * cg + 1) * 1024);
        bf16x8 wf0 = *(const bf16x8*)(wfl + ((0 * 4 + cg) * 64 + l) * 16);
        bf16x8 wf1 = *(const bf16x8*)(wfl + ((1 * 4 + cg) * 64 + l) * 16);
        f32x4 part = (f32x4){0.f, 0.f, 0.f, 0.f};
        part = MFMA(hA0, wf0, part);
        part = MFMA(hA1, wf1, part);
        if (lr < C_) {
#pragma unroll
          for (int jj = 0; jj < 4; ++jj) red[cg][lq * 4 + jj][lr] = part[jj];
        }
      }

      // ha reads (all 8 kt, shared by both s-pairs)
      bf16x8 ha[8];
#pragma unroll
      for (int kt = 0; kt < 8; ++kt)
        ha[kt] = *(const bf16x8*)(hb + rbase + kt * 1024);

      // ---- s-pair {0,1}: MFMA then tanh+write ----
      f32x4 acc01[2];
#pragma unroll
      for (int i = 0; i < 2; ++i) acc01[i] = xw[i];
#pragma unroll
      for (int kt = 0; kt < 8; ++kt)
#pragma unroll
        for (int i = 0; i < 2; ++i) acc01[i] = MFMA(wh[kt][i], ha[kt], acc01[i]);
#pragma unroll
      for (int i = 0; i < 2; ++i) {
        int s = i;
        f32x4 hv;
#pragma unroll
        for (int jj = 0; jj < 4; ++jj) {
          float v = acc01[i][jj];
          float e = __builtin_amdgcn_exp2f(v * TWO_LOG2E);
          float r = __builtin_amdgcn_rcpf(e + 1.0f);
          float hn = __builtin_fmaf(-0.2f, r, __builtin_fmaf(0.9f, h[s][jj], 0.1f));
          h[s][jj] = hn;
          hv[jj] = hn;
        }
        int byte = (cg * 2 + (s >> 1)) * 1024 + lr * 64 +
                   ((((s & 1) * 32) + lq * 8) ^ swzb);
        bf16x4 pk = {(__bf16)hv[0], (__bf16)hv[1], (__bf16)hv[2], (__bf16)hv[3]};
        *(bf16x4*)(hw + byte) = pk;
      }

      // u=1: store logits(tt-1) (red written before u0's barrier)
      if (u == 1 && tt > tout && ow) {
        float sum = red[0][or_][oc_] + red[1][or_][oc_] + red[2][or_][oc_] +
                    red[3][or_][oc_] + bfc_r;
        out[((size_t)(b0 + or_) * C_ + oc_) * T_ + (tt - 1)] = sum;
      }

      // ---- s-pair {2,3}: MFMA then tanh+write (overlaps s01 tanh above) ----
      f32x4 acc23[2];
#pragma unroll
      for (int i = 0; i < 2; ++i) acc23[i] = xw[2 + i];
#pragma unroll
      for (int kt = 0; kt < 8; ++kt)
#pragma unroll
        for (int i = 0; i < 2; ++i) acc23[i] = MFMA(wh[kt][2 + i], ha[kt], acc23[i]);
#pragma unroll
      for (int i = 0; i < 2; ++i) {
        int s = 2 + i;
        f32x4 hv;
#pragma unroll
        for (int jj = 0; jj < 4; ++jj) {
          float v = acc23[i][jj];
          float e = __builtin_amdgcn_exp2f(v * TWO_LOG2E);
          float r = __builtin_amdgcn_rcpf(e + 1.0f);
          float hn = __builtin_fmaf(-0.2f, r, __builtin_fmaf(0.9f, h[s][jj], 0.1f));
          h[s][jj] = hn;
          hv[jj] = hn;
        }
        int byte = (cg * 2 + (s >> 1)) * 1024 + lr * 64 +
                   ((((s & 1) * 32) + lq * 8) ^ swzb);
        bf16x4 pk = {(__bf16)hv[0], (__bf16)hv[1], (__bf16)hv[2], (__bf16)hv[3]};
        *(bf16x4*)(hw + byte) = pk;
      }

      // u=5: xw(tt+1) recomputed in place (x staged into xls at u=4)
      if (u == 5 && tt + 1 < tend) {
        bf16x8 xa[2];
#pragma unroll
        for (int kt = 0; kt < 2; ++kt) {
          int byte = lr * 128 + (kt * 32 + lq * 8) * 2;
          byte ^= (lr & 7) << 4;
          xa[kt] = *(const bf16x8*)(xls + byte);
        }
        f32x4 a_[4];
#pragma unroll
        for (int s = 0; s < 4; ++s) {
          float4 bi = *(const float4*)(bhl + cg * 64 + s * 16 + lq * 4);
          a_[s] = (f32x4){bi.x, bi.y, bi.z, bi.w};
        }
#pragma unroll
        for (int kt = 0; kt < 2; ++kt) {
          bf16x8 wxr[4];
#pragma unroll
          for (int s = 0; s < 4; ++s)
            wxr[s] = *(const bf16x8*)(wxl + (((kt * 4 + s) * 4 + cg) * 64 + l) * 16);
#pragma unroll
          for (int s = 0; s < 4; ++s) a_[s] = MFMA(wxr[s], xa[kt], a_[s]);
        }
#pragma unroll
        for (int s = 0; s < 4; ++s) xw[s] = a_[s];
      }

      if (u == 4 && tt + 1 < tend) {  // stage x(tt+1), rides u4's barrier
        int byte = xrow * 128 + xc * 8;
        byte ^= (xrow & 7) << 4;
        bf16x4 pk = {(__bf16)xpre.x, (__bf16)xpre.y, (__bf16)xpre.z, (__bf16)xpre.w};
        *(bf16x4*)(xls + byte) = pk;
      }
      if (u == 5 && tt + 2 < T_ && tt + 1 < tend)  // prefetch x(tt+2)
        xpre = *(const float4*)(xbase + (size_t)(tt + 2) * I_);
      bar_lds();
    }
  }

  // ================= epilogue: logits(tend-1) =================
  {
    const char* hb = hbuf[0];
    bf16x8 hA0 = *(const bf16x8*)(hb + rbase + (2 * cg) * 1024);
    bf16x8 hA1 = *(const bf16x8*)(hb + rbase + (2 * cg + 1) * 1024);
    bf16x8 wf0 = *(const bf16x8*)(wfl + ((0 * 4 + cg) * 64 + l) * 16);
    bf16x8 wf1 = *(const bf16x8*)(wfl + ((1 * 4 + cg) * 64 + l) * 16);
    f32x4 part = (f32x4){0.f, 0.f, 0.f, 0.f};
    part = MFMA(hA0, wf0, part);
    part = MFMA(hA1, wf1, part);
    if (lr < C_) {
#pragma unroll
      for (int jj = 0; jj < 4; ++jj) red[cg][lq * 4 + jj][lr] = part[jj];
    }
  }
  bar_lds();
  if (ow) {
    float sum = red[0][or_][oc_] + red[1][or_][oc_] + red[2][or_][oc_] +
                red[3][or_][oc_] + bfc_r;
    out[((size_t)(b0 + or_) * C_ + oc_) * T_ + (tend - 1)] = sum;
  }
}

extern "C" void kernel_launch(void* const* d_in, const int* in_sizes, int n_in,
                              void* d_out, int out_size, void* d_ws, size_t ws_size,
                              hipStream_t stream) {
  const float* x   = (const float*)d_in[0];
  const float* W   = (const float*)d_in[1];
  const float* bh  = (const float*)d_in[2];
  const float* Wfc = (const float*)d_in[3];
  const float* bfc = (const float*)d_in[4];
  float* out = (float*)d_out;
  (void)in_sizes; (void)n_in; (void)out_size; (void)d_ws; (void)ws_size;
  ctrnn_fused<<<dim3(512), dim3(256), 0, stream>>>(x, W, bh, Wfc, bfc, out);
}

// Round 21
// 489.498 us; speedup vs baseline: 9.0329x; 1.0741x over previous
//
#include <hip/hip_runtime.h>

// CTRNN fused, v17 = v16 + 2log2(e) folded into Wh/Wx/bias staging (acc is
// already the exp2 argument -> per-elem v_mul deleted) + WARM 16->12.
// Core: transposed MFMA, [kt][row][64B] swizzled hbuf, s-pair pipeline,
// lgkm-only barriers. Resident: wh (128 AGPR); wx/wf/bias in LDS.
// Grid 512 (32 bg x 16 ck), 2 wgs/CU. WARM=12, CHUNK=64.

#define T_ 1024
#define I_ 64
#define H_ 256
#define C_ 5
#define WARM_ 12
#define CHUNK_ 64

typedef float f32x4 __attribute__((ext_vector_type(4)));
typedef __bf16 bf16x8 __attribute__((ext_vector_type(8)));
typedef __bf16 bf16x4 __attribute__((ext_vector_type(4)));
typedef unsigned short ushort_t;
typedef ushort_t ushort8 __attribute__((ext_vector_type(8)));

#define SCALE_ 2.8853900817779268f  // 2*log2(e), folded into Wh/Wx/bias

__device__ __forceinline__ ushort_t f2bf(float x) {  // setup only
  unsigned u = __builtin_bit_cast(unsigned, x);
  return (ushort_t)((u + 0x7FFFu + ((u >> 16) & 1u)) >> 16);
}
__device__ __forceinline__ void bar_lds() {
  __builtin_amdgcn_sched_barrier(0);
  asm volatile("s_waitcnt lgkmcnt(0)" ::: "memory");
  __builtin_amdgcn_s_barrier();
  __builtin_amdgcn_sched_barrier(0);
}
#define MFMA(a, b, c) __builtin_amdgcn_mfma_f32_16x16x32_bf16((a), (b), (c), 0, 0, 0)

__launch_bounds__(256, 2)
__global__ void ctrnn_fused(const float* __restrict__ x, const float* __restrict__ W,
                            const float* __restrict__ bh, const float* __restrict__ Wfc,
                            const float* __restrict__ bfc, float* __restrict__ out) {
  // h ping-pong: [parity][kt:8][row:16][64B]  (8KB per parity)
  __shared__ __align__(16) char hbuf[2][8 * 16 * 64];
  __shared__ __align__(16) char xls[16 * 64 * 2];
  __shared__ __align__(16) char wxl[2 * 4 * 4 * 64 * 16];  // wx fragments, 32KB
  __shared__ __align__(16) char wfl[2 * 4 * 64 * 16];      // wf fragments, 8KB
  __shared__ __align__(16) float bhl[H_];                  // bias (scaled), 1KB
  __shared__ float red[4][16][C_];

  const int tid = threadIdx.x;
  const int cg  = tid >> 6;
  const int l   = tid & 63;
  const int lr  = l & 15;
  const int lq  = l >> 4;
  const int bg  = blockIdx.x & 31;   // batch group
  const int ck  = blockIdx.x >> 5;   // time chunk 0..15
  const int b0  = bg << 4;
  const int tout = ck << 6;
  const int t0   = (ck == 0) ? 0 : (tout - WARM_);
  const int tend = tout + CHUNK_;

  // lane-constant LDS addressing for hbuf
  const int swzb  = ((lr >> 1) & 3) << 4;
  const int rbase = (lr * 64 + lq * 16) ^ swzb;  // + kt*1024 (immediate)

  // ---- resident: wh only (AGPR-eligible), pre-scaled by 2log2(e) ----
  bf16x8 wh[8][4];
#pragma unroll
  for (int kt = 0; kt < 8; ++kt)
#pragma unroll
    for (int s = 0; s < 4; ++s) {
      ushort8 tmp;
#pragma unroll
      for (int j = 0; j < 8; ++j) {
        int k = kt * 32 + lq * 8 + j;
        int col = cg * 64 + s * 16 + lr;
        tmp[j] = f2bf(SCALE_ * W[(size_t)(I_ + k) * H_ + col]);
      }
      wh[kt][s] = __builtin_bit_cast(bf16x8, tmp);
    }
  // wx fragments -> LDS (pre-scaled)
#pragma unroll
  for (int kt = 0; kt < 2; ++kt)
#pragma unroll
    for (int s = 0; s < 4; ++s) {
      ushort8 tmp;
#pragma unroll
      for (int j = 0; j < 8; ++j) {
        int k = kt * 32 + lq * 8 + j;
        int col = cg * 64 + s * 16 + lr;
        tmp[j] = f2bf(SCALE_ * W[(size_t)k * H_ + col]);
      }
      *(bf16x8*)(wxl + (((kt * 4 + s) * 4 + cg) * 64 + l) * 16) =
          __builtin_bit_cast(bf16x8, tmp);
    }
  // wf fragments -> LDS (NOT scaled — logits path uses true h)
#pragma unroll
  for (int kt = 0; kt < 2; ++kt) {
    ushort8 tmp;
#pragma unroll
    for (int j = 0; j < 8; ++j) {
      int k = cg * 64 + kt * 32 + lq * 8 + j;
      tmp[j] = (lr < C_) ? f2bf(Wfc[(size_t)k * C_ + lr]) : (ushort_t)0;
    }
    *(bf16x8*)(wfl + ((kt * 4 + cg) * 64 + l) * 16) = __builtin_bit_cast(bf16x8, tmp);
  }
  // bias -> LDS, pre-scaled
  if (tid < 64) {
    float4 b4 = *(const float4*)(bh + tid * 4);
    b4.x *= SCALE_; b4.y *= SCALE_; b4.z *= SCALE_; b4.w *= SCALE_;
    *(float4*)(bhl + tid * 4) = b4;
  }

  // zero h(-1) parity 0
  ((uint4*)hbuf[0])[tid]       = (uint4){0, 0, 0, 0};
  ((uint4*)hbuf[0])[tid + 256] = (uint4){0, 0, 0, 0};

  const int xrow = tid >> 4, xc = tid & 15;
  const float* xbase = x + (size_t)(b0 + xrow) * T_ * I_ + xc * 4;
  float4 xpre = *(const float4*)(xbase + (size_t)t0 * I_);
  {
    int byte = xrow * 128 + xc * 8;
    byte ^= (xrow & 7) << 4;
    bf16x4 pk = {(__bf16)xpre.x, (__bf16)xpre.y, (__bf16)xpre.z, (__bf16)xpre.w};
    *(bf16x4*)(xls + byte) = pk;
  }
  __syncthreads();

  // xw(t0)  (scaled domain)
  f32x4 xw[4];
  {
    bf16x8 xa[2];
#pragma unroll
    for (int kt = 0; kt < 2; ++kt) {
      int byte = lr * 128 + (kt * 32 + lq * 8) * 2;
      byte ^= (lr & 7) << 4;
      xa[kt] = *(const bf16x8*)(xls + byte);
    }
    f32x4 a_[4];
#pragma unroll
    for (int s = 0; s < 4; ++s) {
      float4 bi = *(const float4*)(bhl + cg * 64 + s * 16 + lq * 4);
      a_[s] = (f32x4){bi.x, bi.y, bi.z, bi.w};
    }
#pragma unroll
    for (int kt = 0; kt < 2; ++kt) {
      bf16x8 wxr[4];
#pragma unroll
      for (int s = 0; s < 4; ++s)
        wxr[s] = *(const bf16x8*)(wxl + (((kt * 4 + s) * 4 + cg) * 64 + l) * 16);
#pragma unroll
      for (int s = 0; s < 4; ++s) a_[s] = MFMA(wxr[s], xa[kt], a_[s]);
    }
#pragma unroll
    for (int s = 0; s < 4; ++s) xw[s] = a_[s];
  }
  xpre = *(const float4*)(xbase + (size_t)(t0 + 1) * I_);

  f32x4 h[4];
#pragma unroll
  for (int s = 0; s < 4; ++s) h[s] = (f32x4){0.f, 0.f, 0.f, 0.f};

  const bool ow = tid < 16 * C_;
  int or_ = 0, oc_ = 0;
  float bfc_r = 0.f;
  if (ow) { or_ = tid / C_; oc_ = tid - or_ * C_; bfc_r = bfc[oc_]; }

#pragma unroll 1
  for (int tt = t0; tt < tend; ++tt) {
#pragma unroll
    for (int u = 0; u < 6; ++u) {
      const char* hb = hbuf[u & 1];
      char* hw = hbuf[(u + 1) & 1];

      // u=0: logits(tt-1) (h(tt-1)-final == hbuf[0] right now)
      if (u == 0 && tt > tout) {
        bf16x8 hA0 = *(const bf16x8*)(hb + rbase + (2 * cg) * 1024);
        bf16x8 hA1 = *(const bf16x8*)(hb + rbase + (2 * cg + 1) * 1024);
        bf16x8 wf0 = *(const bf16x8*)(wfl + ((0 * 4 + cg) * 64 + l) * 16);
        bf16x8 wf1 = *(const bf16x8*)(wfl + ((1 * 4 + cg) * 64 + l) * 16);
        f32x4 part = (f32x4){0.f, 0.f, 0.f, 0.f};
        part = MFMA(hA0, wf0, part);
        part = MFMA(hA1, wf1, part);
        if (lr < C_) {
#pragma unroll
          for (int jj = 0; jj < 4; ++jj) red[cg][lq * 4 + jj][lr] = part[jj];
        }
      }

      // ha reads (all 8 kt, shared by both s-pairs)
      bf16x8 ha[8];
#pragma unroll
      for (int kt = 0; kt < 8; ++kt)
        ha[kt] = *(const bf16x8*)(hb + rbase + kt * 1024);

      // ---- s-pair {0,1}: MFMA then tanh+write ----
      f32x4 acc01[2];
#pragma unroll
      for (int i = 0; i < 2; ++i) acc01[i] = xw[i];
#pragma unroll
      for (int kt = 0; kt < 8; ++kt)
#pragma unroll
        for (int i = 0; i < 2; ++i) acc01[i] = MFMA(wh[kt][i], ha[kt], acc01[i]);
#pragma unroll
      for (int i = 0; i < 2; ++i) {
        int s = i;
        f32x4 hv;
#pragma unroll
        for (int jj = 0; jj < 4; ++jj) {
          float e = __builtin_amdgcn_exp2f(acc01[i][jj]);   // acc = 2log2e*v
          float r = __builtin_amdgcn_rcpf(e + 1.0f);
          float hn = __builtin_fmaf(-0.2f, r, __builtin_fmaf(0.9f, h[s][jj], 0.1f));
          h[s][jj] = hn;
          hv[jj] = hn;
        }
        int byte = (cg * 2 + (s >> 1)) * 1024 + lr * 64 +
                   ((((s & 1) * 32) + lq * 8) ^ swzb);
        bf16x4 pk = {(__bf16)hv[0], (__bf16)hv[1], (__bf16)hv[2], (__bf16)hv[3]};
        *(bf16x4*)(hw + byte) = pk;
      }

      // u=1: store logits(tt-1) (red written before u0's barrier)
      if (u == 1 && tt > tout && ow) {
        float sum = red[0][or_][oc_] + red[1][or_][oc_] + red[2][or_][oc_] +
                    red[3][or_][oc_] + bfc_r;
        out[((size_t)(b0 + or_) * C_ + oc_) * T_ + (tt - 1)] = sum;
      }

      // ---- s-pair {2,3}: MFMA then tanh+write (overlaps s01 tanh) ----
      f32x4 acc23[2];
#pragma unroll
      for (int i = 0; i < 2; ++i) acc23[i] = xw[2 + i];
#pragma unroll
      for (int kt = 0; kt < 8; ++kt)
#pragma unroll
        for (int i = 0; i < 2; ++i) acc23[i] = MFMA(wh[kt][2 + i], ha[kt], acc23[i]);
#pragma unroll
      for (int i = 0; i < 2; ++i) {
        int s = 2 + i;
        f32x4 hv;
#pragma unroll
        for (int jj = 0; jj < 4; ++jj) {
          float e = __builtin_amdgcn_exp2f(acc23[i][jj]);
          float r = __builtin_amdgcn_rcpf(e + 1.0f);
          float hn = __builtin_fmaf(-0.2f, r, __builtin_fmaf(0.9f, h[s][jj], 0.1f));
          h[s][jj] = hn;
          hv[jj] = hn;
        }
        int byte = (cg * 2 + (s >> 1)) * 1024 + lr * 64 +
                   ((((s & 1) * 32) + lq * 8) ^ swzb);
        bf16x4 pk = {(__bf16)hv[0], (__bf16)hv[1], (__bf16)hv[2], (__bf16)hv[3]};
        *(bf16x4*)(hw + byte) = pk;
      }

      // u=5: xw(tt+1) recomputed in place (x staged into xls at u=4)
      if (u == 5 && tt + 1 < tend) {
        bf16x8 xa[2];
#pragma unroll
        for (int kt = 0; kt < 2; ++kt) {
          int byte = lr * 128 + (kt * 32 + lq * 8) * 2;
          byte ^= (lr & 7) << 4;
          xa[kt] = *(const bf16x8*)(xls + byte);
        }
        f32x4 a_[4];
#pragma unroll
        for (int s = 0; s < 4; ++s) {
          float4 bi = *(const float4*)(bhl + cg * 64 + s * 16 + lq * 4);
          a_[s] = (f32x4){bi.x, bi.y, bi.z, bi.w};
        }
#pragma unroll
        for (int kt = 0; kt < 2; ++kt) {
          bf16x8 wxr[4];
#pragma unroll
          for (int s = 0; s < 4; ++s)
            wxr[s] = *(const bf16x8*)(wxl + (((kt * 4 + s) * 4 + cg) * 64 + l) * 16);
#pragma unroll
          for (int s = 0; s < 4; ++s) a_[s] = MFMA(wxr[s], xa[kt], a_[s]);
        }
#pragma unroll
        for (int s = 0; s < 4; ++s) xw[s] = a_[s];
      }

      if (u == 4 && tt + 1 < tend) {  // stage x(tt+1), rides u4's barrier
        int byte = xrow * 128 + xc * 8;
        byte ^= (xrow & 7) << 4;
        bf16x4 pk = {(__bf16)xpre.x, (__bf16)xpre.y, (__bf16)xpre.z, (__bf16)xpre.w};
        *(bf16x4*)(xls + byte) = pk;
      }
      if (u == 5 && tt + 2 < T_ && tt + 1 < tend)  // prefetch x(tt+2)
        xpre = *(const float4*)(xbase + (size_t)(tt + 2) * I_);
      bar_lds();
    }
  }

  // ================= epilogue: logits(tend-1) =================
  {
    const char* hb = hbuf[0];
    bf16x8 hA0 = *(const bf16x8*)(hb + rbase + (2 * cg) * 1024);
    bf16x8 hA1 = *(const bf16x8*)(hb + rbase + (2 * cg + 1) * 1024);
    bf16x8 wf0 = *(const bf16x8*)(wfl + ((0 * 4 + cg) * 64 + l) * 16);
    bf16x8 wf1 = *(const bf16x8*)(wfl + ((1 * 4 + cg) * 64 + l) * 16);
    f32x4 part = (f32x4){0.f, 0.f, 0.f, 0.f};
    part = MFMA(hA0, wf0, part);
    part = MFMA(hA1, wf1, part);
    if (lr < C_) {
#pragma unroll
      for (int jj = 0; jj < 4; ++jj) red[cg][lq * 4 + jj][lr] = part[jj];
    }
  }
  bar_lds();
  if (ow) {
    float sum = red[0][or_][oc_] + red[1][or_][oc_] + red[2][or_][oc_] +
                red[3][or_][oc_] + bfc_r;
    out[((size_t)(b0 + or_) * C_ + oc_) * T_ + (tend - 1)] = sum;
  }
}

extern "C" void kernel_launch(void* const* d_in, const int* in_sizes, int n_in,
                              void* d_out, int out_size, void* d_ws, size_t ws_size,
                              hipStream_t stream) {
  const float* x   = (const float*)d_in[0];
  const float* W   = (const float*)d_in[1];
  const float* bh  = (const float*)d_in[2];
  const float* Wfc = (const float*)d_in[3];
  const float* bfc = (const float*)d_in[4];
  float* out = (float*)d_out;
  (void)in_sizes; (void)n_in; (void)out_size; (void)d_ws; (void)ws_size;
  ctrnn_fused<<<dim3(512), dim3(256), 0, stream>>>(x, W, bh, Wfc, bfc, out);
}